// Round 1
// baseline (1034.875 us; speedup 1.0000x reference)
//
#include <hip/hip_runtime.h>
#include <math.h>

#define BB   16
#define LL   512
#define DD   512
#define HH   8
#define HDIM 64
#define NITER 50

// ---------------- wave-wide reductions (64 lanes) ----------------
__device__ __forceinline__ float wsum(float v) {
    v += __shfl_xor(v, 1);  v += __shfl_xor(v, 2);  v += __shfl_xor(v, 4);
    v += __shfl_xor(v, 8);  v += __shfl_xor(v, 16); v += __shfl_xor(v, 32);
    return v;
}
__device__ __forceinline__ float wmax(float v) {
    v = fmaxf(v, __shfl_xor(v, 1));  v = fmaxf(v, __shfl_xor(v, 2));
    v = fmaxf(v, __shfl_xor(v, 4));  v = fmaxf(v, __shfl_xor(v, 8));
    v = fmaxf(v, __shfl_xor(v, 16)); v = fmaxf(v, __shfl_xor(v, 32));
    return v;
}

// p(z) = max(z,0)^e  (e = 1/(alpha-1) > 0)
__device__ __forceinline__ float pfun(float z, float e) {
    // speculative log of non-positive gives NaN but is selected away
    float r = exp2f(__log2f(z) * e);
    return (z > 0.f) ? r : 0.f;
}

// ---------------- generic tiled fp32 GEMM: C = act(A @ W^T + bias) [+ resid] ----------------
// A: [M,K] row-major, W: [N,K] row-major, C: [M,N]
#define BM 64
#define BN 64
#define BK 32

template<int ACT, bool RES>
__global__ __launch_bounds__(256) void gemm_bias_kernel(
    const float* __restrict__ A, const float* __restrict__ W,
    const float* __restrict__ bias, const float* __restrict__ resid,
    float* __restrict__ C, int M, int N, int K)
{
    __shared__ float Ast[BK][BM + 4];  // transposed tiles, 16B-aligned rows
    __shared__ float Wst[BK][BN + 4];

    const int bm = blockIdx.y * BM;
    const int bn = blockIdx.x * BN;
    const int tid = threadIdx.x;
    const int tx = tid & 15, ty = tid >> 4;
    const int m0 = ty * 4, n0 = tx * 4;

    float acc[4][4] = {};

    for (int kt = 0; kt < K; kt += BK) {
        const int r  = tid >> 3;           // 0..31
        const int c4 = (tid & 7) * 4;      // 0..28
        float4 a0 = *(const float4*)&A[(size_t)(bm + r)      * K + kt + c4];
        float4 a1 = *(const float4*)&A[(size_t)(bm + r + 32) * K + kt + c4];
        float4 w0 = *(const float4*)&W[(size_t)(bn + r)      * K + kt + c4];
        float4 w1 = *(const float4*)&W[(size_t)(bn + r + 32) * K + kt + c4];
        Ast[c4+0][r] = a0.x; Ast[c4+1][r] = a0.y; Ast[c4+2][r] = a0.z; Ast[c4+3][r] = a0.w;
        Ast[c4+0][r+32] = a1.x; Ast[c4+1][r+32] = a1.y; Ast[c4+2][r+32] = a1.z; Ast[c4+3][r+32] = a1.w;
        Wst[c4+0][r] = w0.x; Wst[c4+1][r] = w0.y; Wst[c4+2][r] = w0.z; Wst[c4+3][r] = w0.w;
        Wst[c4+0][r+32] = w1.x; Wst[c4+1][r+32] = w1.y; Wst[c4+2][r+32] = w1.z; Wst[c4+3][r+32] = w1.w;
        __syncthreads();

        #pragma unroll
        for (int k = 0; k < BK; ++k) {
            float4 av = *(const float4*)&Ast[k][m0];
            float4 wv = *(const float4*)&Wst[k][n0];
            acc[0][0] = fmaf(av.x, wv.x, acc[0][0]); acc[0][1] = fmaf(av.x, wv.y, acc[0][1]);
            acc[0][2] = fmaf(av.x, wv.z, acc[0][2]); acc[0][3] = fmaf(av.x, wv.w, acc[0][3]);
            acc[1][0] = fmaf(av.y, wv.x, acc[1][0]); acc[1][1] = fmaf(av.y, wv.y, acc[1][1]);
            acc[1][2] = fmaf(av.y, wv.z, acc[1][2]); acc[1][3] = fmaf(av.y, wv.w, acc[1][3]);
            acc[2][0] = fmaf(av.z, wv.x, acc[2][0]); acc[2][1] = fmaf(av.z, wv.y, acc[2][1]);
            acc[2][2] = fmaf(av.z, wv.z, acc[2][2]); acc[2][3] = fmaf(av.z, wv.w, acc[2][3]);
            acc[3][0] = fmaf(av.w, wv.x, acc[3][0]); acc[3][1] = fmaf(av.w, wv.y, acc[3][1]);
            acc[3][2] = fmaf(av.w, wv.z, acc[3][2]); acc[3][3] = fmaf(av.w, wv.w, acc[3][3]);
        }
        __syncthreads();
    }

    #pragma unroll
    for (int ii = 0; ii < 4; ++ii) {
        const int m = bm + m0 + ii;
        #pragma unroll
        for (int jj = 0; jj < 4; ++jj) {
            const int n = bn + n0 + jj;
            float v = acc[ii][jj] + bias[n];
            if (ACT == 1) v = fmaxf(v, 0.f);
            if (RES) v += resid[(size_t)m * N + n];
            C[(size_t)m * N + n] = v;
        }
    }
}

// ---------------- Kt[b,h][d][j] = X[b,j,h*64+d] ----------------
__global__ __launch_bounds__(256) void transpose_kt(const float* __restrict__ X,
                                                    float* __restrict__ Kt)
{
    int o = blockIdx.x * 256 + threadIdx.x;     // 0 .. 4194303, j fastest
    int j = o & 511;
    int d = (o >> 9) & 63;
    int h = (o >> 15) & 7;
    int b = o >> 18;
    Kt[o] = X[((b << 9) + j) * 512 + h * 64 + d];
}

// ---------------- alpha per (b,h) from q[b, L-1, h,:] ----------------
__global__ void alpha_kernel(const float* __restrict__ Q, const float* __restrict__ Wa,
                             const float* __restrict__ ba,
                             float* __restrict__ am1v, float* __restrict__ invv)
{
    int t = threadIdx.x;
    if (t >= BB * HH) return;
    int b = t >> 3, h = t & 7;
    float acc = 0.f;
    #pragma unroll
    for (int d = 0; d < HDIM; ++d)
        acc = fmaf(Q[((b << 9) + 511) * 512 + h * 64 + d], Wa[d], acc);
    acc += ba[0];
    float sig = 1.f / (1.f + expf(-acc));
    float alpha = sig + 1.f;
    const float amin = 1.f + 1e-5f;
    if (alpha < amin) alpha = amin;
    float am1 = alpha - 1.f;
    am1v[t] = am1;
    invv[t] = 1.f / am1;
}

// ---------------- fused scores -> entmax-bisect -> PV, one wave per query row ----------------
__global__ __launch_bounds__(256) void attn_kernel(
    const float* __restrict__ Q, const float* __restrict__ X, const float* __restrict__ Kt,
    const float* __restrict__ mask, const float* __restrict__ am1v,
    const float* __restrict__ invv, float* __restrict__ ATT)
{
    __shared__ float qs[4][64];
    __shared__ float ps[4][512];

    const int w = threadIdx.x >> 6, lane = threadIdx.x & 63;
    const int row = blockIdx.x * 4 + w;          // (b*8+h)*512 + i
    const int b = row >> 12;
    const int h = (row >> 9) & 7;
    const int i = row & 511;

    qs[w][lane] = Q[((b << 9) + i) * 512 + (h << 6) + lane];
    __syncthreads();

    const float am1 = am1v[(b << 3) + h];
    const float inv = invv[(b << 3) + h];
    const float* KtBH = Kt + (size_t)((b << 3) + h) * 64 * 512;

    // scores: s[j] = q . k_j / 8,  j = r*64 + lane
    float sacc[8] = {0,0,0,0,0,0,0,0};
    #pragma unroll 8
    for (int d = 0; d < 64; ++d) {
        float qd = qs[w][d];
        const float* kp = KtBH + d * 512 + lane;
        #pragma unroll
        for (int r = 0; r < 8; ++r) sacc[r] = fmaf(qd, kp[r * 64], sacc[r]);
    }

    float Xs[8];
    #pragma unroll
    for (int r = 0; r < 8; ++r) {
        int j = r * 64 + lane;
        float mval = (j < 511) ? mask[b * 511 + j] : 0.f;   // last key always masked
        Xs[r] = (mval == 0.f) ? -__builtin_inff() : sacc[r] * 0.125f * am1;
    }

    // entmax bisection (faithful port)
    float mx = Xs[0];
    #pragma unroll
    for (int r = 1; r < 8; ++r) mx = fmaxf(mx, Xs[r]);
    mx = wmax(mx);

    float tau_lo = mx - 1.f;
    float tau_hi = mx - exp2f(-9.f * am1);       // (1/512)^am1
    float dm = tau_hi - tau_lo;

    float s0 = 0.f;
    #pragma unroll
    for (int r = 0; r < 8; ++r) s0 += pfun(Xs[r] - tau_lo, inv);
    const float f_lo = wsum(s0) - 1.f;

    float tau_m = tau_lo;
    for (int it = 0; it < NITER; ++it) {
        dm *= 0.5f;
        tau_m = tau_lo + dm;
        float loc = 0.f;
        #pragma unroll
        for (int r = 0; r < 8; ++r) loc += pfun(Xs[r] - tau_m, inv);
        float f_m = wsum(loc) - 1.f;
        if (f_m * f_lo >= 0.f) tau_lo = tau_m;
    }

    float pr[8], loc = 0.f;
    #pragma unroll
    for (int r = 0; r < 8; ++r) { pr[r] = pfun(Xs[r] - tau_m, inv); loc += pr[r]; }
    float tot = wsum(loc);
    float rn = 1.f / tot;
    #pragma unroll
    for (int r = 0; r < 8; ++r) ps[w][r * 64 + lane] = pr[r] * rn;
    __syncthreads();

    // PV: att[d=lane] = sum_j p[j] * X[b,j,h*64+lane]
    float acc = 0.f;
    const float* xp = X + (size_t)(b << 9) * 512 + (h << 6) + lane;
    #pragma unroll 8
    for (int j = 0; j < 512; ++j) acc = fmaf(ps[w][j], xp[(size_t)j * 512], acc);
    ATT[((b << 9) + i) * 512 + (h << 6) + lane] = acc;
}

// ---------------- LayerNorm + scatter to split outputs ----------------
__global__ __launch_bounds__(256) void ln_kernel(const float* __restrict__ Cb,
                                                 const float* __restrict__ g,
                                                 const float* __restrict__ beta,
                                                 float* __restrict__ out)
{
    const int w = threadIdx.x >> 6, lane = threadIdx.x & 63;
    const int row = blockIdx.x * 4 + w;          // 0..8191
    const int b = row >> 9, l = row & 511;
    const float* x = Cb + (size_t)row * 512;

    float v[8], s = 0.f;
    #pragma unroll
    for (int k = 0; k < 8; ++k) { v[k] = x[k * 64 + lane]; s += v[k]; }
    s = wsum(s);
    float mu = s * (1.f / 512.f);
    float q = 0.f;
    #pragma unroll
    for (int k = 0; k < 8; ++k) { float d = v[k] - mu; q = fmaf(d, d, q); }
    q = wsum(q);
    float rs = rsqrtf(q * (1.f / 512.f) + 1e-12f);

    float* dst = (l < 511) ? (out + (size_t)(b * 511 + l) * 512)
                           : (out + (size_t)16 * 511 * 512 + (size_t)b * 512);
    #pragma unroll
    for (int k = 0; k < 8; ++k) {
        int d = k * 64 + lane;
        dst[d] = (v[k] - mu) * rs * g[d] + beta[d];
    }
}

// ---------------- launch ----------------
extern "C" void kernel_launch(void* const* d_in, const int* in_sizes, int n_in,
                              void* d_out, int out_size, void* d_ws, size_t ws_size,
                              hipStream_t stream)
{
    const float* X    = (const float*)d_in[0];
    const float* mask = (const float*)d_in[1];
    const float* Wq   = (const float*)d_in[2];
    const float* bq   = (const float*)d_in[3];
    const float* W1   = (const float*)d_in[4];
    const float* b1   = (const float*)d_in[5];
    const float* W2   = (const float*)d_in[6];
    const float* b2   = (const float*)d_in[7];
    const float* lng  = (const float*)d_in[8];
    const float* lnb  = (const float*)d_in[9];
    const float* Wa   = (const float*)d_in[10];
    const float* ba   = (const float*)d_in[11];
    float* out = (float*)d_out;
    float* ws  = (float*)d_ws;

    const size_t NE = (size_t)BB * LL * DD;      // 4194304
    if (ws_size < (3 * NE + 256) * sizeof(float)) return;

    float* Qb   = ws;            // q-proj output; later reused for FFN output
    float* Kt   = ws + NE;       // transposed keys; later reused for FFN hidden
    float* ATT  = ws + 2 * NE;
    float* am1v = ws + 3 * NE;
    float* invv = am1v + 128;
    float* Hh = Kt;
    float* Cb = Qb;

    const int M = BB * LL;       // 8192

    gemm_bias_kernel<1, false><<<dim3(DD / BN, M / BM), 256, 0, stream>>>(
        X, Wq, bq, nullptr, Qb, M, DD, DD);
    transpose_kt<<<(int)(NE / 256), 256, 0, stream>>>(X, Kt);
    alpha_kernel<<<1, 128, 0, stream>>>(Qb, Wa, ba, am1v, invv);
    attn_kernel<<<BB * HH * LL / 4, 256, 0, stream>>>(Qb, X, Kt, mask, am1v, invv, ATT);
    gemm_bias_kernel<1, false><<<dim3(DD / BN, M / BM), 256, 0, stream>>>(
        ATT, W1, b1, nullptr, Hh, M, DD, DD);
    gemm_bias_kernel<0, true><<<dim3(DD / BN, M / BM), 256, 0, stream>>>(
        Hh, W2, b2, ATT, Cb, M, DD, DD);
    ln_kernel<<<M / 4, 256, 0, stream>>>(Cb, lng, lnb, out);
}

// Round 2
// 695.002 us; speedup vs baseline: 1.4890x; 1.4890x over previous
//
#include <hip/hip_runtime.h>
#include <math.h>

#define BB   16
#define LL   512
#define DD   512
#define HH   8
#define HDIM 64
#define NITER 20

// ---------------- wave-wide reductions ----------------
__device__ __forceinline__ float wsum(float v) {
    v += __shfl_xor(v, 1);  v += __shfl_xor(v, 2);  v += __shfl_xor(v, 4);
    v += __shfl_xor(v, 8);  v += __shfl_xor(v, 16); v += __shfl_xor(v, 32);
    return v;
}
// reduce within 16-lane groups (4 independent rows per wave)
__device__ __forceinline__ float gsum16(float v) {
    v += __shfl_xor(v, 1); v += __shfl_xor(v, 2);
    v += __shfl_xor(v, 4); v += __shfl_xor(v, 8);
    return v;
}
__device__ __forceinline__ float gmax16(float v) {
    v = fmaxf(v, __shfl_xor(v, 1)); v = fmaxf(v, __shfl_xor(v, 2));
    v = fmaxf(v, __shfl_xor(v, 4)); v = fmaxf(v, __shfl_xor(v, 8));
    return v;
}

// p(z) = max(z,0)^e ; log2(0) = -inf -> exp2(-inf) = 0, no select needed
__device__ __forceinline__ float pf(float z, float e) {
    z = fmaxf(z, 0.f);
    return exp2f(__log2f(z) * e);
}

// ---------------- generic tiled fp32 GEMM: C = act(A @ W^T + bias) [+ resid] ----------------
#define BM 64
#define BN 64
#define BK 32

template<int ACT, bool RES>
__global__ __launch_bounds__(256) void gemm_bias_kernel(
    const float* __restrict__ A, const float* __restrict__ W,
    const float* __restrict__ bias, const float* __restrict__ resid,
    float* __restrict__ C, int M, int N, int K)
{
    __shared__ float Ast[BK][BM + 4];
    __shared__ float Wst[BK][BN + 4];

    const int bm = blockIdx.y * BM;
    const int bn = blockIdx.x * BN;
    const int tid = threadIdx.x;
    const int tx = tid & 15, ty = tid >> 4;
    const int m0 = ty * 4, n0 = tx * 4;

    float acc[4][4] = {};

    for (int kt = 0; kt < K; kt += BK) {
        const int r  = tid >> 3;
        const int c4 = (tid & 7) * 4;
        float4 a0 = *(const float4*)&A[(size_t)(bm + r)      * K + kt + c4];
        float4 a1 = *(const float4*)&A[(size_t)(bm + r + 32) * K + kt + c4];
        float4 w0 = *(const float4*)&W[(size_t)(bn + r)      * K + kt + c4];
        float4 w1 = *(const float4*)&W[(size_t)(bn + r + 32) * K + kt + c4];
        Ast[c4+0][r] = a0.x; Ast[c4+1][r] = a0.y; Ast[c4+2][r] = a0.z; Ast[c4+3][r] = a0.w;
        Ast[c4+0][r+32] = a1.x; Ast[c4+1][r+32] = a1.y; Ast[c4+2][r+32] = a1.z; Ast[c4+3][r+32] = a1.w;
        Wst[c4+0][r] = w0.x; Wst[c4+1][r] = w0.y; Wst[c4+2][r] = w0.z; Wst[c4+3][r] = w0.w;
        Wst[c4+0][r+32] = w1.x; Wst[c4+1][r+32] = w1.y; Wst[c4+2][r+32] = w1.z; Wst[c4+3][r+32] = w1.w;
        __syncthreads();

        #pragma unroll
        for (int k = 0; k < BK; ++k) {
            float4 av = *(const float4*)&Ast[k][m0];
            float4 wv = *(const float4*)&Wst[k][n0];
            acc[0][0] = fmaf(av.x, wv.x, acc[0][0]); acc[0][1] = fmaf(av.x, wv.y, acc[0][1]);
            acc[0][2] = fmaf(av.x, wv.z, acc[0][2]); acc[0][3] = fmaf(av.x, wv.w, acc[0][3]);
            acc[1][0] = fmaf(av.y, wv.x, acc[1][0]); acc[1][1] = fmaf(av.y, wv.y, acc[1][1]);
            acc[1][2] = fmaf(av.y, wv.z, acc[1][2]); acc[1][3] = fmaf(av.y, wv.w, acc[1][3]);
            acc[2][0] = fmaf(av.z, wv.x, acc[2][0]); acc[2][1] = fmaf(av.z, wv.y, acc[2][1]);
            acc[2][2] = fmaf(av.z, wv.z, acc[2][2]); acc[2][3] = fmaf(av.z, wv.w, acc[2][3]);
            acc[3][0] = fmaf(av.w, wv.x, acc[3][0]); acc[3][1] = fmaf(av.w, wv.y, acc[3][1]);
            acc[3][2] = fmaf(av.w, wv.z, acc[3][2]); acc[3][3] = fmaf(av.w, wv.w, acc[3][3]);
        }
        __syncthreads();
    }

    #pragma unroll
    for (int ii = 0; ii < 4; ++ii) {
        const int m = bm + m0 + ii;
        #pragma unroll
        for (int jj = 0; jj < 4; ++jj) {
            const int n = bn + n0 + jj;
            float v = acc[ii][jj] + bias[n];
            if (ACT == 1) v = fmaxf(v, 0.f);
            if (RES) v += resid[(size_t)m * N + n];
            C[(size_t)m * N + n] = v;
        }
    }
}

// ---------------- Kt[b,h][d][j] = X[b,j,h*64+d] ----------------
__global__ __launch_bounds__(256) void transpose_kt(const float* __restrict__ X,
                                                    float* __restrict__ Kt)
{
    int o = blockIdx.x * 256 + threadIdx.x;
    int j = o & 511;
    int d = (o >> 9) & 63;
    int h = (o >> 15) & 7;
    int b = o >> 18;
    Kt[o] = X[((b << 9) + j) * 512 + h * 64 + d];
}

// ---------------- alpha per (b,h) ----------------
__global__ void alpha_kernel(const float* __restrict__ Q, const float* __restrict__ Wa,
                             const float* __restrict__ ba,
                             float* __restrict__ am1v, float* __restrict__ invv)
{
    int t = threadIdx.x;
    if (t >= BB * HH) return;
    int b = t >> 3, h = t & 7;
    float acc = 0.f;
    #pragma unroll
    for (int d = 0; d < HDIM; ++d)
        acc = fmaf(Q[((b << 9) + 511) * 512 + h * 64 + d], Wa[d], acc);
    acc += ba[0];
    float sig = 1.f / (1.f + expf(-acc));
    float alpha = sig + 1.f;
    const float amin = 1.f + 1e-5f;
    if (alpha < amin) alpha = amin;
    float am1 = alpha - 1.f;
    am1v[t] = am1;
    invv[t] = 1.f / am1;
}

// ---------------- fused attention: 16 rows/block, LDS-shared K & X tiles ----------------
// block = 256 threads (4 waves); wave w owns block-rows w*4 .. w*4+3.
// Bisection layout: each 16-lane group owns one row, 32 elems/lane (j = e*16 + lane&15).
__global__ __launch_bounds__(256) void attn_kernel(
    const float* __restrict__ Q, const float* __restrict__ X, const float* __restrict__ Kt,
    const float* __restrict__ mask, const float* __restrict__ am1v,
    const float* __restrict__ invv, float* __restrict__ ATT)
{
    __shared__ float qs[16][68];       // q rows, padded
    __shared__ float SL[16][516];      // scores, then normalized p
    __shared__ float stage[8704];      // K chunk [64][132] or X chunk [128][68]

    const int bh = blockIdx.x >> 5;    // b*8+h
    const int rg = blockIdx.x & 31;    // row-group (16 rows)
    const int b = bh >> 3, h = bh & 7;
    const int tid = threadIdx.x;
    const int w = tid >> 6, lane = tid & 63;

    const float am1 = am1v[bh];
    const float inv = invv[bh];
    const float* KtBH = Kt + (size_t)bh * 64 * 512;

    // ---- phase A: load q rows ----
    #pragma unroll
    for (int it = 0; it < 4; ++it) {
        int idx = tid + it * 256;               // 0..1023
        int rr = idx >> 6, d = idx & 63;
        qs[rr][d] = Q[((b << 9) + rg * 16 + rr) * 512 + (h << 6) + d];
    }
    __syncthreads();

    // ---- phase B: scores, 4 chunks of 128 j ----
    // wave computes its 4 rows; j = c*128 + 2*lane + u
    for (int c = 0; c < 4; ++c) {
        // stage K chunk: KS[d][jj] = Kt[d*512 + c*128 + jj], layout stride 132
        #pragma unroll
        for (int u = 0; u < 8; ++u) {
            int l4 = tid * 8 + u;               // 0..2047
            int d = l4 >> 5, q4 = (l4 & 31) * 4;
            *(float4*)&stage[d * 132 + q4] =
                *(const float4*)&KtBH[d * 512 + c * 128 + q4];
        }
        __syncthreads();

        float s00 = 0.f, s01 = 0.f, s10 = 0.f, s11 = 0.f;
        float s20 = 0.f, s21 = 0.f, s30 = 0.f, s31 = 0.f;
        #pragma unroll 16
        for (int d = 0; d < 64; ++d) {
            float2 kv = *(const float2*)&stage[d * 132 + 2 * lane];
            float q0 = qs[w * 4 + 0][d];
            float q1 = qs[w * 4 + 1][d];
            float q2 = qs[w * 4 + 2][d];
            float q3 = qs[w * 4 + 3][d];
            s00 = fmaf(q0, kv.x, s00); s01 = fmaf(q0, kv.y, s01);
            s10 = fmaf(q1, kv.x, s10); s11 = fmaf(q1, kv.y, s11);
            s20 = fmaf(q2, kv.x, s20); s21 = fmaf(q2, kv.y, s21);
            s30 = fmaf(q3, kv.x, s30); s31 = fmaf(q3, kv.y, s31);
        }
        int jb = c * 128 + 2 * lane;
        *(float2*)&SL[w * 4 + 0][jb] = make_float2(s00, s01);
        *(float2*)&SL[w * 4 + 1][jb] = make_float2(s10, s11);
        *(float2*)&SL[w * 4 + 2][jb] = make_float2(s20, s21);
        *(float2*)&SL[w * 4 + 3][jb] = make_float2(s30, s31);
        __syncthreads();
    }

    // ---- phase C: entmax bisection, 16-lane group per row ----
    const int lp = lane & 15, g = lane >> 4;
    const int row = w * 4 + g;                   // block-local 0..15
    const float NEG = -__builtin_inff();

    float Xs[32];
    #pragma unroll
    for (int e = 0; e < 32; ++e) {
        int j = e * 16 + lp;
        float sv = SL[row][j];
        float mv = (j < 511) ? mask[b * 511 + j] : 0.f;  // last key always masked
        Xs[e] = (mv == 0.f) ? NEG : sv * 0.125f * am1;
    }

    float mx = Xs[0];
    #pragma unroll
    for (int e = 1; e < 32; ++e) mx = fmaxf(mx, Xs[e]);
    mx = gmax16(mx);

    float tau_lo = mx - 1.f;
    float tau_hi = mx - exp2f(-9.f * am1);       // (1/512)^am1
    float dm = tau_hi - tau_lo;

    {   // f_lo (sign only matters, but keep faithful)
        float a0 = 0.f, a1 = 0.f, a2 = 0.f, a3 = 0.f;
        #pragma unroll
        for (int e = 0; e < 32; e += 4) {
            a0 += pf(Xs[e + 0] - tau_lo, inv);
            a1 += pf(Xs[e + 1] - tau_lo, inv);
            a2 += pf(Xs[e + 2] - tau_lo, inv);
            a3 += pf(Xs[e + 3] - tau_lo, inv);
        }
        float f_lo = gsum16((a0 + a1) + (a2 + a3)) - 1.f;

        float tau_m = tau_lo;
        for (int it = 0; it < NITER; ++it) {
            dm *= 0.5f;
            tau_m = tau_lo + dm;
            float b0 = 0.f, b1 = 0.f, b2 = 0.f, b3 = 0.f;
            #pragma unroll
            for (int e = 0; e < 32; e += 4) {
                b0 += pf(Xs[e + 0] - tau_m, inv);
                b1 += pf(Xs[e + 1] - tau_m, inv);
                b2 += pf(Xs[e + 2] - tau_m, inv);
                b3 += pf(Xs[e + 3] - tau_m, inv);
            }
            float f_m = gsum16((b0 + b1) + (b2 + b3)) - 1.f;
            tau_lo = (f_m * f_lo >= 0.f) ? tau_m : tau_lo;
        }

        float pr[32];
        float t0 = 0.f, t1 = 0.f, t2 = 0.f, t3 = 0.f;
        #pragma unroll
        for (int e = 0; e < 32; e += 4) {
            pr[e + 0] = pf(Xs[e + 0] - tau_m, inv); t0 += pr[e + 0];
            pr[e + 1] = pf(Xs[e + 1] - tau_m, inv); t1 += pr[e + 1];
            pr[e + 2] = pf(Xs[e + 2] - tau_m, inv); t2 += pr[e + 2];
            pr[e + 3] = pf(Xs[e + 3] - tau_m, inv); t3 += pr[e + 3];
        }
        float tot = gsum16((t0 + t1) + (t2 + t3));
        float rn = 1.f / tot;
        #pragma unroll
        for (int e = 0; e < 32; ++e) SL[row][e * 16 + lp] = pr[e] * rn;
    }
    // no cross-wave barrier needed: each wave reads back only its own SL rows.

    // ---- phase D: PV, 4 chunks of 128 j; att[d=lane] per row ----
    float att0 = 0.f, att1 = 0.f, att2 = 0.f, att3 = 0.f;
    for (int c = 0; c < 4; ++c) {
        __syncthreads();   // ensure all waves done reading `stage` (B) / prior chunk
        // stage X chunk: XS[jj][dd] = X[(b*512 + c*128 + jj)*512 + h*64 + dd], stride 68
        #pragma unroll
        for (int u = 0; u < 8; ++u) {
            int l4 = tid * 8 + u;               // 0..2047
            int jj = l4 >> 4, d4 = (l4 & 15) * 4;
            *(float4*)&stage[jj * 68 + d4] =
                *(const float4*)&X[((size_t)(b << 9) + c * 128 + jj) * 512 + (h << 6) + d4];
        }
        __syncthreads();

        #pragma unroll 8
        for (int j4 = 0; j4 < 32; ++j4) {
            float4 p0 = *(const float4*)&SL[w * 4 + 0][c * 128 + j4 * 4];
            float4 p1 = *(const float4*)&SL[w * 4 + 1][c * 128 + j4 * 4];
            float4 p2 = *(const float4*)&SL[w * 4 + 2][c * 128 + j4 * 4];
            float4 p3 = *(const float4*)&SL[w * 4 + 3][c * 128 + j4 * 4];
            #pragma unroll
            for (int q = 0; q < 4; ++q) {
                float xv = stage[(j4 * 4 + q) * 68 + lane];
                float pq0 = (q == 0) ? p0.x : (q == 1) ? p0.y : (q == 2) ? p0.z : p0.w;
                float pq1 = (q == 0) ? p1.x : (q == 1) ? p1.y : (q == 2) ? p1.z : p1.w;
                float pq2 = (q == 0) ? p2.x : (q == 1) ? p2.y : (q == 2) ? p2.z : p2.w;
                float pq3 = (q == 0) ? p3.x : (q == 1) ? p3.y : (q == 2) ? p3.z : p3.w;
                att0 = fmaf(pq0, xv, att0);
                att1 = fmaf(pq1, xv, att1);
                att2 = fmaf(pq2, xv, att2);
                att3 = fmaf(pq3, xv, att3);
            }
        }
    }

    {
        int ibase = rg * 16 + w * 4;
        ATT[((size_t)(b << 9) + ibase + 0) * 512 + (h << 6) + lane] = att0;
        ATT[((size_t)(b << 9) + ibase + 1) * 512 + (h << 6) + lane] = att1;
        ATT[((size_t)(b << 9) + ibase + 2) * 512 + (h << 6) + lane] = att2;
        ATT[((size_t)(b << 9) + ibase + 3) * 512 + (h << 6) + lane] = att3;
    }
}

// ---------------- LayerNorm + scatter ----------------
__global__ __launch_bounds__(256) void ln_kernel(const float* __restrict__ Cb,
                                                 const float* __restrict__ g,
                                                 const float* __restrict__ beta,
                                                 float* __restrict__ out)
{
    const int w = threadIdx.x >> 6, lane = threadIdx.x & 63;
    const int row = blockIdx.x * 4 + w;
    const int b = row >> 9, l = row & 511;
    const float* x = Cb + (size_t)row * 512;

    float v[8], s = 0.f;
    #pragma unroll
    for (int k = 0; k < 8; ++k) { v[k] = x[k * 64 + lane]; s += v[k]; }
    s = wsum(s);
    float mu = s * (1.f / 512.f);
    float q = 0.f;
    #pragma unroll
    for (int k = 0; k < 8; ++k) { float d = v[k] - mu; q = fmaf(d, d, q); }
    q = wsum(q);
    float rs = rsqrtf(q * (1.f / 512.f) + 1e-12f);

    float* dst = (l < 511) ? (out + (size_t)(b * 511 + l) * 512)
                           : (out + (size_t)16 * 511 * 512 + (size_t)b * 512);
    #pragma unroll
    for (int k = 0; k < 8; ++k) {
        int d = k * 64 + lane;
        dst[d] = (v[k] - mu) * rs * g[d] + beta[d];
    }
}

// ---------------- launch ----------------
extern "C" void kernel_launch(void* const* d_in, const int* in_sizes, int n_in,
                              void* d_out, int out_size, void* d_ws, size_t ws_size,
                              hipStream_t stream)
{
    const float* X    = (const float*)d_in[0];
    const float* mask = (const float*)d_in[1];
    const float* Wq   = (const float*)d_in[2];
    const float* bq   = (const float*)d_in[3];
    const float* W1   = (const float*)d_in[4];
    const float* b1   = (const float*)d_in[5];
    const float* W2   = (const float*)d_in[6];
    const float* b2   = (const float*)d_in[7];
    const float* lng  = (const float*)d_in[8];
    const float* lnb  = (const float*)d_in[9];
    const float* Wa   = (const float*)d_in[10];
    const float* ba   = (const float*)d_in[11];
    float* out = (float*)d_out;
    float* ws  = (float*)d_ws;

    const size_t NE = (size_t)BB * LL * DD;      // 4194304
    if (ws_size < (3 * NE + 256) * sizeof(float)) return;

    float* Qb   = ws;
    float* Kt   = ws + NE;
    float* ATT  = ws + 2 * NE;
    float* am1v = ws + 3 * NE;
    float* invv = am1v + 128;
    float* Hh = Kt;
    float* Cb = Qb;

    const int M = BB * LL;       // 8192

    gemm_bias_kernel<1, false><<<dim3(DD / BN, M / BM), 256, 0, stream>>>(
        X, Wq, bq, nullptr, Qb, M, DD, DD);
    transpose_kt<<<(int)(NE / 256), 256, 0, stream>>>(X, Kt);
    alpha_kernel<<<1, 128, 0, stream>>>(Qb, Wa, ba, am1v, invv);
    attn_kernel<<<BB * HH * LL / 16, 256, 0, stream>>>(Qb, X, Kt, mask, am1v, invv, ATT);
    gemm_bias_kernel<1, false><<<dim3(DD / BN, M / BM), 256, 0, stream>>>(
        ATT, W1, b1, nullptr, Hh, M, DD, DD);
    gemm_bias_kernel<0, true><<<dim3(DD / BN, M / BM), 256, 0, stream>>>(
        Hh, W2, b2, ATT, Cb, M, DD, DD);
    ln_kernel<<<M / 4, 256, 0, stream>>>(Cb, lng, lnb, out);
}

// Round 3
// 688.862 us; speedup vs baseline: 1.5023x; 1.0089x over previous
//
#include <hip/hip_runtime.h>
#include <math.h>

#define BB   16
#define LL   512
#define DD   512
#define HH   8
#define HDIM 64
#define NITER 20

// single-instruction hardware transcendentals (v_log_f32 / v_exp_f32)
extern "C" __device__ float __ocml_native_log2_f32(float);
extern "C" __device__ float __ocml_native_exp2_f32(float);

// ---------------- wave-wide reductions ----------------
__device__ __forceinline__ float wsum(float v) {
    v += __shfl_xor(v, 1);  v += __shfl_xor(v, 2);  v += __shfl_xor(v, 4);
    v += __shfl_xor(v, 8);  v += __shfl_xor(v, 16); v += __shfl_xor(v, 32);
    return v;
}
// reduce within 16-lane groups (4 independent rows per wave)
__device__ __forceinline__ float gsum16(float v) {
    v += __shfl_xor(v, 1); v += __shfl_xor(v, 2);
    v += __shfl_xor(v, 4); v += __shfl_xor(v, 8);
    return v;
}
__device__ __forceinline__ float gmax16(float v) {
    v = fmaxf(v, __shfl_xor(v, 1)); v = fmaxf(v, __shfl_xor(v, 2));
    v = fmaxf(v, __shfl_xor(v, 4)); v = fmaxf(v, __shfl_xor(v, 8));
    return v;
}

// p(z) = max(z,0)^e ; v_log_f32(0) = -inf -> v_exp_f32(-inf) = 0, clamp is free
__device__ __forceinline__ float pf(float z, float e) {
    z = fmaxf(z, 0.f);
    return __ocml_native_exp2_f32(__ocml_native_log2_f32(z) * e);
}

// ---------------- generic tiled fp32 GEMM: C = act(A @ W^T + bias) [+ resid] ----------------
#define BM 64
#define BN 64
#define BK 32

template<int ACT, bool RES>
__global__ __launch_bounds__(256) void gemm_bias_kernel(
    const float* __restrict__ A, const float* __restrict__ W,
    const float* __restrict__ bias, const float* __restrict__ resid,
    float* __restrict__ C, int M, int N, int K)
{
    __shared__ float Ast[BK][BM + 4];
    __shared__ float Wst[BK][BN + 4];

    const int bm = blockIdx.y * BM;
    const int bn = blockIdx.x * BN;
    const int tid = threadIdx.x;
    const int tx = tid & 15, ty = tid >> 4;
    const int m0 = ty * 4, n0 = tx * 4;

    float acc[4][4] = {};

    for (int kt = 0; kt < K; kt += BK) {
        const int r  = tid >> 3;
        const int c4 = (tid & 7) * 4;
        float4 a0 = *(const float4*)&A[(size_t)(bm + r)      * K + kt + c4];
        float4 a1 = *(const float4*)&A[(size_t)(bm + r + 32) * K + kt + c4];
        float4 w0 = *(const float4*)&W[(size_t)(bn + r)      * K + kt + c4];
        float4 w1 = *(const float4*)&W[(size_t)(bn + r + 32) * K + kt + c4];
        Ast[c4+0][r] = a0.x; Ast[c4+1][r] = a0.y; Ast[c4+2][r] = a0.z; Ast[c4+3][r] = a0.w;
        Ast[c4+0][r+32] = a1.x; Ast[c4+1][r+32] = a1.y; Ast[c4+2][r+32] = a1.z; Ast[c4+3][r+32] = a1.w;
        Wst[c4+0][r] = w0.x; Wst[c4+1][r] = w0.y; Wst[c4+2][r] = w0.z; Wst[c4+3][r] = w0.w;
        Wst[c4+0][r+32] = w1.x; Wst[c4+1][r+32] = w1.y; Wst[c4+2][r+32] = w1.z; Wst[c4+3][r+32] = w1.w;
        __syncthreads();

        #pragma unroll
        for (int k = 0; k < BK; ++k) {
            float4 av = *(const float4*)&Ast[k][m0];
            float4 wv = *(const float4*)&Wst[k][n0];
            acc[0][0] = fmaf(av.x, wv.x, acc[0][0]); acc[0][1] = fmaf(av.x, wv.y, acc[0][1]);
            acc[0][2] = fmaf(av.x, wv.z, acc[0][2]); acc[0][3] = fmaf(av.x, wv.w, acc[0][3]);
            acc[1][0] = fmaf(av.y, wv.x, acc[1][0]); acc[1][1] = fmaf(av.y, wv.y, acc[1][1]);
            acc[1][2] = fmaf(av.y, wv.z, acc[1][2]); acc[1][3] = fmaf(av.y, wv.w, acc[1][3]);
            acc[2][0] = fmaf(av.z, wv.x, acc[2][0]); acc[2][1] = fmaf(av.z, wv.y, acc[2][1]);
            acc[2][2] = fmaf(av.z, wv.z, acc[2][2]); acc[2][3] = fmaf(av.z, wv.w, acc[2][3]);
            acc[3][0] = fmaf(av.w, wv.x, acc[3][0]); acc[3][1] = fmaf(av.w, wv.y, acc[3][1]);
            acc[3][2] = fmaf(av.w, wv.z, acc[3][2]); acc[3][3] = fmaf(av.w, wv.w, acc[3][3]);
        }
        __syncthreads();
    }

    #pragma unroll
    for (int ii = 0; ii < 4; ++ii) {
        const int m = bm + m0 + ii;
        #pragma unroll
        for (int jj = 0; jj < 4; ++jj) {
            const int n = bn + n0 + jj;
            float v = acc[ii][jj] + bias[n];
            if (ACT == 1) v = fmaxf(v, 0.f);
            if (RES) v += resid[(size_t)m * N + n];
            C[(size_t)m * N + n] = v;
        }
    }
}

// ---------------- Kt[b,h][d][j] = X[b,j,h*64+d] ----------------
__global__ __launch_bounds__(256) void transpose_kt(const float* __restrict__ X,
                                                    float* __restrict__ Kt)
{
    int o = blockIdx.x * 256 + threadIdx.x;
    int j = o & 511;
    int d = (o >> 9) & 63;
    int h = (o >> 15) & 7;
    int b = o >> 18;
    Kt[o] = X[((b << 9) + j) * 512 + h * 64 + d];
}

// ---------------- alpha per (b,h) ----------------
__global__ void alpha_kernel(const float* __restrict__ Q, const float* __restrict__ Wa,
                             const float* __restrict__ ba,
                             float* __restrict__ am1v, float* __restrict__ invv)
{
    int t = threadIdx.x;
    if (t >= BB * HH) return;
    int b = t >> 3, h = t & 7;
    float acc = 0.f;
    #pragma unroll
    for (int d = 0; d < HDIM; ++d)
        acc = fmaf(Q[((b << 9) + 511) * 512 + h * 64 + d], Wa[d], acc);
    acc += ba[0];
    float sig = 1.f / (1.f + expf(-acc));
    float alpha = sig + 1.f;
    const float amin = 1.f + 1e-5f;
    if (alpha < amin) alpha = amin;
    float am1 = alpha - 1.f;
    am1v[t] = am1;
    invv[t] = 1.f / am1;
}

// ---------------- fused attention: 16 rows/block, LDS-shared K & X tiles ----------------
// SL stride 520: row-to-row bank offset = 8, so the four 16-lane groups cover
// banks {0..15},{8..23},{16..31},{24..7} -> exactly 2 lanes/bank (free on CDNA4).
#define SLS 520
__global__ __launch_bounds__(256) void attn_kernel(
    const float* __restrict__ Q, const float* __restrict__ X, const float* __restrict__ Kt,
    const float* __restrict__ mask, const float* __restrict__ am1v,
    const float* __restrict__ invv, float* __restrict__ ATT)
{
    __shared__ float qs[16][68];       // q rows, padded
    __shared__ float SL[16][SLS];      // scores, then normalized p
    __shared__ float stage[8704];      // K chunk [64][132] or X chunk [128][68]

    const int bh = blockIdx.x >> 5;    // b*8+h
    const int rg = blockIdx.x & 31;    // row-group (16 rows)
    const int b = bh >> 3, h = bh & 7;
    const int tid = threadIdx.x;
    const int w = tid >> 6, lane = tid & 63;

    const float am1 = am1v[bh];
    const float inv = invv[bh];
    const float* KtBH = Kt + (size_t)bh * 64 * 512;

    // ---- phase A: load q rows ----
    #pragma unroll
    for (int it = 0; it < 4; ++it) {
        int idx = tid + it * 256;               // 0..1023
        int rr = idx >> 6, d = idx & 63;
        qs[rr][d] = Q[((b << 9) + rg * 16 + rr) * 512 + (h << 6) + d];
    }
    __syncthreads();

    // ---- phase B: scores, 4 chunks of 128 j ----
    for (int c = 0; c < 4; ++c) {
        #pragma unroll
        for (int u = 0; u < 8; ++u) {
            int l4 = tid * 8 + u;               // 0..2047
            int d = l4 >> 5, q4 = (l4 & 31) * 4;
            *(float4*)&stage[d * 132 + q4] =
                *(const float4*)&KtBH[d * 512 + c * 128 + q4];
        }
        __syncthreads();

        float s00 = 0.f, s01 = 0.f, s10 = 0.f, s11 = 0.f;
        float s20 = 0.f, s21 = 0.f, s30 = 0.f, s31 = 0.f;
        #pragma unroll 16
        for (int d = 0; d < 64; ++d) {
            float2 kv = *(const float2*)&stage[d * 132 + 2 * lane];
            float q0 = qs[w * 4 + 0][d];
            float q1 = qs[w * 4 + 1][d];
            float q2 = qs[w * 4 + 2][d];
            float q3 = qs[w * 4 + 3][d];
            s00 = fmaf(q0, kv.x, s00); s01 = fmaf(q0, kv.y, s01);
            s10 = fmaf(q1, kv.x, s10); s11 = fmaf(q1, kv.y, s11);
            s20 = fmaf(q2, kv.x, s20); s21 = fmaf(q2, kv.y, s21);
            s30 = fmaf(q3, kv.x, s30); s31 = fmaf(q3, kv.y, s31);
        }
        int jb = c * 128 + 2 * lane;
        *(float2*)&SL[w * 4 + 0][jb] = make_float2(s00, s01);
        *(float2*)&SL[w * 4 + 1][jb] = make_float2(s10, s11);
        *(float2*)&SL[w * 4 + 2][jb] = make_float2(s20, s21);
        *(float2*)&SL[w * 4 + 3][jb] = make_float2(s30, s31);
        __syncthreads();
    }

    // ---- phase C: entmax bisection, 16-lane group per row ----
    const int lp = lane & 15, g = lane >> 4;
    const int row = w * 4 + g;                   // block-local 0..15
    const float NEG = -__builtin_inff();

    float Xs[32];
    #pragma unroll
    for (int e = 0; e < 32; ++e) {
        int j = e * 16 + lp;
        float sv = SL[row][j];
        float mv = (j < 511) ? mask[b * 511 + j] : 0.f;  // last key always masked
        Xs[e] = (mv == 0.f) ? NEG : sv * 0.125f * am1;
    }

    float mx = Xs[0];
    #pragma unroll
    for (int e = 1; e < 32; ++e) mx = fmaxf(mx, Xs[e]);
    mx = gmax16(mx);

    float tau_lo = mx - 1.f;
    float tau_hi = mx - __ocml_native_exp2_f32(-9.f * am1);   // (1/512)^am1
    float dm = tau_hi - tau_lo;

    {
        float a0 = 0.f, a1 = 0.f, a2 = 0.f, a3 = 0.f;
        #pragma unroll
        for (int e = 0; e < 32; e += 4) {
            a0 += pf(Xs[e + 0] - tau_lo, inv);
            a1 += pf(Xs[e + 1] - tau_lo, inv);
            a2 += pf(Xs[e + 2] - tau_lo, inv);
            a3 += pf(Xs[e + 3] - tau_lo, inv);
        }
        float f_lo = gsum16((a0 + a1) + (a2 + a3)) - 1.f;

        float tau_m = tau_lo;
        for (int it = 0; it < NITER; ++it) {
            dm *= 0.5f;
            tau_m = tau_lo + dm;
            float b0 = 0.f, b1 = 0.f, b2 = 0.f, b3 = 0.f;
            #pragma unroll
            for (int e = 0; e < 32; e += 4) {
                b0 += pf(Xs[e + 0] - tau_m, inv);
                b1 += pf(Xs[e + 1] - tau_m, inv);
                b2 += pf(Xs[e + 2] - tau_m, inv);
                b3 += pf(Xs[e + 3] - tau_m, inv);
            }
            float f_m = gsum16((b0 + b1) + (b2 + b3)) - 1.f;
            tau_lo = (f_m * f_lo >= 0.f) ? tau_m : tau_lo;
        }

        float pr[32];
        float t0 = 0.f, t1 = 0.f, t2 = 0.f, t3 = 0.f;
        #pragma unroll
        for (int e = 0; e < 32; e += 4) {
            pr[e + 0] = pf(Xs[e + 0] - tau_m, inv); t0 += pr[e + 0];
            pr[e + 1] = pf(Xs[e + 1] - tau_m, inv); t1 += pr[e + 1];
            pr[e + 2] = pf(Xs[e + 2] - tau_m, inv); t2 += pr[e + 2];
            pr[e + 3] = pf(Xs[e + 3] - tau_m, inv); t3 += pr[e + 3];
        }
        float tot = gsum16((t0 + t1) + (t2 + t3));
        float rn = 1.f / tot;
        #pragma unroll
        for (int e = 0; e < 32; ++e) SL[row][e * 16 + lp] = pr[e] * rn;
    }
    // no cross-wave barrier needed: each wave reads back only its own SL rows.

    // ---- phase D: PV, 4 chunks of 128 j; att[d=lane] per row ----
    float att0 = 0.f, att1 = 0.f, att2 = 0.f, att3 = 0.f;
    for (int c = 0; c < 4; ++c) {
        __syncthreads();   // ensure all waves done with `stage` before overwrite
        #pragma unroll
        for (int u = 0; u < 8; ++u) {
            int l4 = tid * 8 + u;               // 0..2047
            int jj = l4 >> 4, d4 = (l4 & 15) * 4;
            *(float4*)&stage[jj * 68 + d4] =
                *(const float4*)&X[((size_t)(b << 9) + c * 128 + jj) * 512 + (h << 6) + d4];
        }
        __syncthreads();

        #pragma unroll 8
        for (int j4 = 0; j4 < 32; ++j4) {
            float4 p0 = *(const float4*)&SL[w * 4 + 0][c * 128 + j4 * 4];
            float4 p1 = *(const float4*)&SL[w * 4 + 1][c * 128 + j4 * 4];
            float4 p2 = *(const float4*)&SL[w * 4 + 2][c * 128 + j4 * 4];
            float4 p3 = *(const float4*)&SL[w * 4 + 3][c * 128 + j4 * 4];
            #pragma unroll
            for (int q = 0; q < 4; ++q) {
                float xv = stage[(j4 * 4 + q) * 68 + lane];
                float pq0 = (q == 0) ? p0.x : (q == 1) ? p0.y : (q == 2) ? p0.z : p0.w;
                float pq1 = (q == 0) ? p1.x : (q == 1) ? p1.y : (q == 2) ? p1.z : p1.w;
                float pq2 = (q == 0) ? p2.x : (q == 1) ? p2.y : (q == 2) ? p2.z : p2.w;
                float pq3 = (q == 0) ? p3.x : (q == 1) ? p3.y : (q == 2) ? p3.z : p3.w;
                att0 = fmaf(pq0, xv, att0);
                att1 = fmaf(pq1, xv, att1);
                att2 = fmaf(pq2, xv, att2);
                att3 = fmaf(pq3, xv, att3);
            }
        }
    }

    {
        int ibase = rg * 16 + w * 4;
        ATT[((size_t)(b << 9) + ibase + 0) * 512 + (h << 6) + lane] = att0;
        ATT[((size_t)(b << 9) + ibase + 1) * 512 + (h << 6) + lane] = att1;
        ATT[((size_t)(b << 9) + ibase + 2) * 512 + (h << 6) + lane] = att2;
        ATT[((size_t)(b << 9) + ibase + 3) * 512 + (h << 6) + lane] = att3;
    }
}

// ---------------- LayerNorm + scatter ----------------
__global__ __launch_bounds__(256) void ln_kernel(const float* __restrict__ Cb,
                                                 const float* __restrict__ g,
                                                 const float* __restrict__ beta,
                                                 float* __restrict__ out)
{
    const int w = threadIdx.x >> 6, lane = threadIdx.x & 63;
    const int row = blockIdx.x * 4 + w;
    const int b = row >> 9, l = row & 511;
    const float* x = Cb + (size_t)row * 512;

    float v[8], s = 0.f;
    #pragma unroll
    for (int k = 0; k < 8; ++k) { v[k] = x[k * 64 + lane]; s += v[k]; }
    s = wsum(s);
    float mu = s * (1.f / 512.f);
    float q = 0.f;
    #pragma unroll
    for (int k = 0; k < 8; ++k) { float d = v[k] - mu; q = fmaf(d, d, q); }
    q = wsum(q);
    float rs = rsqrtf(q * (1.f / 512.f) + 1e-12f);

    float* dst = (l < 511) ? (out + (size_t)(b * 511 + l) * 512)
                           : (out + (size_t)16 * 511 * 512 + (size_t)b * 512);
    #pragma unroll
    for (int k = 0; k < 8; ++k) {
        int d = k * 64 + lane;
        dst[d] = (v[k] - mu) * rs * g[d] + beta[d];
    }
}

// ---------------- launch ----------------
extern "C" void kernel_launch(void* const* d_in, const int* in_sizes, int n_in,
                              void* d_out, int out_size, void* d_ws, size_t ws_size,
                              hipStream_t stream)
{
    const float* X    = (const float*)d_in[0];
    const float* mask = (const float*)d_in[1];
    const float* Wq   = (const float*)d_in[2];
    const float* bq   = (const float*)d_in[3];
    const float* W1   = (const float*)d_in[4];
    const float* b1   = (const float*)d_in[5];
    const float* W2   = (const float*)d_in[6];
    const float* b2   = (const float*)d_in[7];
    const float* lng  = (const float*)d_in[8];
    const float* lnb  = (const float*)d_in[9];
    const float* Wa   = (const float*)d_in[10];
    const float* ba   = (const float*)d_in[11];
    float* out = (float*)d_out;
    float* ws  = (float*)d_ws;

    const size_t NE = (size_t)BB * LL * DD;      // 4194304
    if (ws_size < (3 * NE + 256) * sizeof(float)) return;

    float* Qb   = ws;
    float* Kt   = ws + NE;
    float* ATT  = ws + 2 * NE;
    float* am1v = ws + 3 * NE;
    float* invv = am1v + 128;
    float* Hh = Kt;
    float* Cb = Qb;

    const int M = BB * LL;       // 8192

    gemm_bias_kernel<1, false><<<dim3(DD / BN, M / BM), 256, 0, stream>>>(
        X, Wq, bq, nullptr, Qb, M, DD, DD);
    transpose_kt<<<(int)(NE / 256), 256, 0, stream>>>(X, Kt);
    alpha_kernel<<<1, 128, 0, stream>>>(Qb, Wa, ba, am1v, invv);
    attn_kernel<<<BB * HH * LL / 16, 256, 0, stream>>>(Qb, X, Kt, mask, am1v, invv, ATT);
    gemm_bias_kernel<1, false><<<dim3(DD / BN, M / BM), 256, 0, stream>>>(
        ATT, W1, b1, nullptr, Hh, M, DD, DD);
    gemm_bias_kernel<0, true><<<dim3(DD / BN, M / BM), 256, 0, stream>>>(
        Hh, W2, b2, ATT, Cb, M, DD, DD);
    ln_kernel<<<M / 4, 256, 0, stream>>>(Cb, lng, lnb, out);
}

// Round 4
// 535.542 us; speedup vs baseline: 1.9324x; 1.2863x over previous
//
#include <hip/hip_runtime.h>
#include <math.h>

#define BB   16
#define LL   512
#define DD   512
#define HH   8
#define HDIM 64
#define NNEWT 12

// raw single-instruction transcendentals
__device__ __forceinline__ float hw_log2(float x) { return __builtin_amdgcn_logf(x); }
__device__ __forceinline__ float hw_exp2(float x) { return __builtin_amdgcn_exp2f(x); }

// ---------------- wave-wide reduction (64 lanes) for ln ----------------
__device__ __forceinline__ float wsum(float v) {
    v += __shfl_xor(v, 1);  v += __shfl_xor(v, 2);  v += __shfl_xor(v, 4);
    v += __shfl_xor(v, 8);  v += __shfl_xor(v, 16); v += __shfl_xor(v, 32);
    return v;
}

// ---------------- DPP 16-lane-group butterflies (full-rate VALU, no LDS) ----------------
template<int CTRL>
__device__ __forceinline__ float dpp_mov(float v) {
    return __builtin_bit_cast(float, __builtin_amdgcn_update_dpp(
        0, __builtin_bit_cast(int, v), CTRL, 0xf, 0xf, true));
}
__device__ __forceinline__ float rsum16(float v) {
    v += dpp_mov<0xB1>(v);    // quad_perm [1,0,3,2]  (xor 1)
    v += dpp_mov<0x4E>(v);    // quad_perm [2,3,0,1]  (xor 2)
    v += dpp_mov<0x141>(v);   // row_half_mirror      (swap quads within 8)
    v += dpp_mov<0x140>(v);   // row_mirror           (swap 8-halves within 16)
    return v;
}
__device__ __forceinline__ float rmax16(float v) {
    v = fmaxf(v, dpp_mov<0xB1>(v));
    v = fmaxf(v, dpp_mov<0x4E>(v));
    v = fmaxf(v, dpp_mov<0x141>(v));
    v = fmaxf(v, dpp_mov<0x140>(v));
    return v;
}

// ---------------- generic tiled fp32 GEMM: C = act(A @ W^T + bias) [+ resid] ----------------
#define BM 64
#define BN 64
#define BK 32

template<int ACT, bool RES>
__global__ __launch_bounds__(256) void gemm_bias_kernel(
    const float* __restrict__ A, const float* __restrict__ W,
    const float* __restrict__ bias, const float* __restrict__ resid,
    float* __restrict__ C, int M, int N, int K)
{
    __shared__ float Ast[BK][BM + 4];
    __shared__ float Wst[BK][BN + 4];

    const int bm = blockIdx.y * BM;
    const int bn = blockIdx.x * BN;
    const int tid = threadIdx.x;
    const int tx = tid & 15, ty = tid >> 4;
    const int m0 = ty * 4, n0 = tx * 4;

    float acc[4][4] = {};

    for (int kt = 0; kt < K; kt += BK) {
        const int r  = tid >> 3;
        const int c4 = (tid & 7) * 4;
        float4 a0 = *(const float4*)&A[(size_t)(bm + r)      * K + kt + c4];
        float4 a1 = *(const float4*)&A[(size_t)(bm + r + 32) * K + kt + c4];
        float4 w0 = *(const float4*)&W[(size_t)(bn + r)      * K + kt + c4];
        float4 w1 = *(const float4*)&W[(size_t)(bn + r + 32) * K + kt + c4];
        Ast[c4+0][r] = a0.x; Ast[c4+1][r] = a0.y; Ast[c4+2][r] = a0.z; Ast[c4+3][r] = a0.w;
        Ast[c4+0][r+32] = a1.x; Ast[c4+1][r+32] = a1.y; Ast[c4+2][r+32] = a1.z; Ast[c4+3][r+32] = a1.w;
        Wst[c4+0][r] = w0.x; Wst[c4+1][r] = w0.y; Wst[c4+2][r] = w0.z; Wst[c4+3][r] = w0.w;
        Wst[c4+0][r+32] = w1.x; Wst[c4+1][r+32] = w1.y; Wst[c4+2][r+32] = w1.z; Wst[c4+3][r+32] = w1.w;
        __syncthreads();

        #pragma unroll
        for (int k = 0; k < BK; ++k) {
            float4 av = *(const float4*)&Ast[k][m0];
            float4 wv = *(const float4*)&Wst[k][n0];
            acc[0][0] = fmaf(av.x, wv.x, acc[0][0]); acc[0][1] = fmaf(av.x, wv.y, acc[0][1]);
            acc[0][2] = fmaf(av.x, wv.z, acc[0][2]); acc[0][3] = fmaf(av.x, wv.w, acc[0][3]);
            acc[1][0] = fmaf(av.y, wv.x, acc[1][0]); acc[1][1] = fmaf(av.y, wv.y, acc[1][1]);
            acc[1][2] = fmaf(av.y, wv.z, acc[1][2]); acc[1][3] = fmaf(av.y, wv.w, acc[1][3]);
            acc[2][0] = fmaf(av.z, wv.x, acc[2][0]); acc[2][1] = fmaf(av.z, wv.y, acc[2][1]);
            acc[2][2] = fmaf(av.z, wv.z, acc[2][2]); acc[2][3] = fmaf(av.z, wv.w, acc[2][3]);
            acc[3][0] = fmaf(av.w, wv.x, acc[3][0]); acc[3][1] = fmaf(av.w, wv.y, acc[3][1]);
            acc[3][2] = fmaf(av.w, wv.z, acc[3][2]); acc[3][3] = fmaf(av.w, wv.w, acc[3][3]);
        }
        __syncthreads();
    }

    #pragma unroll
    for (int ii = 0; ii < 4; ++ii) {
        const int m = bm + m0 + ii;
        #pragma unroll
        for (int jj = 0; jj < 4; ++jj) {
            const int n = bn + n0 + jj;
            float v = acc[ii][jj] + bias[n];
            if (ACT == 1) v = fmaxf(v, 0.f);
            if (RES) v += resid[(size_t)m * N + n];
            C[(size_t)m * N + n] = v;
        }
    }
}

// ---------------- Kt[b,h][d][j] = X[b,j,h*64+d] ----------------
__global__ __launch_bounds__(256) void transpose_kt(const float* __restrict__ X,
                                                    float* __restrict__ Kt)
{
    int o = blockIdx.x * 256 + threadIdx.x;
    int j = o & 511;
    int d = (o >> 9) & 63;
    int h = (o >> 15) & 7;
    int b = o >> 18;
    Kt[o] = X[((b << 9) + j) * 512 + h * 64 + d];
}

// ---------------- alpha per (b,h) ----------------
__global__ void alpha_kernel(const float* __restrict__ Q, const float* __restrict__ Wa,
                             const float* __restrict__ ba,
                             float* __restrict__ am1v, float* __restrict__ invv)
{
    int t = threadIdx.x;
    if (t >= BB * HH) return;
    int b = t >> 3, h = t & 7;
    float acc = 0.f;
    #pragma unroll
    for (int d = 0; d < HDIM; ++d)
        acc = fmaf(Q[((b << 9) + 511) * 512 + h * 64 + d], Wa[d], acc);
    acc += ba[0];
    float sig = 1.f / (1.f + expf(-acc));
    float alpha = sig + 1.f;
    const float amin = 1.f + 1e-5f;
    if (alpha < amin) alpha = amin;
    float am1 = alpha - 1.f;
    am1v[t] = am1;
    invv[t] = 1.f / am1;
}

// ---------------- fused attention v3 ----------------
// 16 rows/block, 4 waves; K and X read directly from global (L2-resident with
// XCD swizzle). LDS = q rows + score/p buffer only (38 KB -> 4 blocks/CU).
// Single barrier. Entmax tau via 12 monotone Newton iterations (f convex
// decreasing, start at tau_lo where f>=0 -> never overshoots).
#define SLS 520
__global__ __launch_bounds__(256, 4) void attn_kernel(
    const float* __restrict__ Q, const float* __restrict__ X, const float* __restrict__ Kt,
    const float* __restrict__ mask, const float* __restrict__ am1v,
    const float* __restrict__ invv, float* __restrict__ ATT)
{
    __shared__ float qs[16][68];
    __shared__ float SL[16][SLS];

    // XCD swizzle: 4096 blocks = 8 XCDs x 512; the 32 blocks sharing a (b,h)
    // become consecutive on ONE XCD -> Kt/X slices stay in its L2.
    const int bid = ((blockIdx.x & 7) << 9) + (blockIdx.x >> 3);
    const int bh = bid >> 5;
    const int rg = bid & 31;
    const int b = bh >> 3, h = bh & 7;
    const int tid = threadIdx.x;
    const int w = tid >> 6, lane = tid & 63;

    const float am1 = am1v[bh];
    const float inv = invv[bh];
    const float im1 = inv - 1.f;
    const float* KtBH = Kt + (size_t)bh * (64 * 512);

    // ---- phase A: stage q rows ----
    #pragma unroll
    for (int it = 0; it < 4; ++it) {
        int idx = tid + it * 256;               // 0..1023
        int rr = idx >> 6, d = idx & 63;
        qs[rr][d] = Q[((b << 9) + rg * 16 + rr) * 512 + (h << 6) + d];
    }
    __syncthreads();   // the only barrier

    // ---- phase B: scores straight from global Kt; 2 chunks x 256 j ----
    // wave w computes rows w*4..w*4+3; lane covers j = c*256 + 4*lane + {0..3}
    #pragma unroll
    for (int c = 0; c < 2; ++c) {
        float acc[4][4] = {{0,0,0,0},{0,0,0,0},{0,0,0,0},{0,0,0,0}};
        const float* kp = KtBH + c * 256 + 4 * lane;
        #pragma unroll
        for (int d4 = 0; d4 < 16; ++d4) {
            float4 qv0 = *(const float4*)&qs[w*4+0][d4*4];
            float4 qv1 = *(const float4*)&qs[w*4+1][d4*4];
            float4 qv2 = *(const float4*)&qs[w*4+2][d4*4];
            float4 qv3 = *(const float4*)&qs[w*4+3][d4*4];
            #pragma unroll
            for (int dd = 0; dd < 4; ++dd) {
                float4 kv = *(const float4*)&kp[(size_t)(d4*4+dd) * 512];
                float q0 = dd==0?qv0.x:dd==1?qv0.y:dd==2?qv0.z:qv0.w;
                float q1 = dd==0?qv1.x:dd==1?qv1.y:dd==2?qv1.z:qv1.w;
                float q2 = dd==0?qv2.x:dd==1?qv2.y:dd==2?qv2.z:qv2.w;
                float q3 = dd==0?qv3.x:dd==1?qv3.y:dd==2?qv3.z:qv3.w;
                acc[0][0]=fmaf(q0,kv.x,acc[0][0]); acc[0][1]=fmaf(q0,kv.y,acc[0][1]);
                acc[0][2]=fmaf(q0,kv.z,acc[0][2]); acc[0][3]=fmaf(q0,kv.w,acc[0][3]);
                acc[1][0]=fmaf(q1,kv.x,acc[1][0]); acc[1][1]=fmaf(q1,kv.y,acc[1][1]);
                acc[1][2]=fmaf(q1,kv.z,acc[1][2]); acc[1][3]=fmaf(q1,kv.w,acc[1][3]);
                acc[2][0]=fmaf(q2,kv.x,acc[2][0]); acc[2][1]=fmaf(q2,kv.y,acc[2][1]);
                acc[2][2]=fmaf(q2,kv.z,acc[2][2]); acc[2][3]=fmaf(q2,kv.w,acc[2][3]);
                acc[3][0]=fmaf(q3,kv.x,acc[3][0]); acc[3][1]=fmaf(q3,kv.y,acc[3][1]);
                acc[3][2]=fmaf(q3,kv.z,acc[3][2]); acc[3][3]=fmaf(q3,kv.w,acc[3][3]);
            }
        }
        int jb = c * 256 + 4 * lane;
        *(float4*)&SL[w*4+0][jb] = make_float4(acc[0][0],acc[0][1],acc[0][2],acc[0][3]);
        *(float4*)&SL[w*4+1][jb] = make_float4(acc[1][0],acc[1][1],acc[1][2],acc[1][3]);
        *(float4*)&SL[w*4+2][jb] = make_float4(acc[2][0],acc[2][1],acc[2][2],acc[2][3]);
        *(float4*)&SL[w*4+3][jb] = make_float4(acc[3][0],acc[3][1],acc[3][2],acc[3][3]);
    }
    // intra-wave LDS dependency only -> no barrier

    // ---- phase C: entmax via monotone Newton, 16-lane group per row ----
    const int lp = lane & 15, g = lane >> 4;
    const int row = w * 4 + g;
    const float NEG = -__builtin_inff();

    float Xs[32];
    #pragma unroll
    for (int e = 0; e < 32; ++e) {
        int j = e * 16 + lp;
        float sv = SL[row][j];
        float mv = (j < 511) ? mask[b * 511 + j] : 0.f;  // last key always masked
        Xs[e] = (mv == 0.f) ? NEG : sv * 0.125f * am1;
    }

    float mx = Xs[0];
    #pragma unroll
    for (int e = 1; e < 32; ++e) mx = fmaxf(mx, Xs[e]);
    mx = rmax16(mx);

    // Newton from tau_lo = mx - 1 (f(tau_lo) >= 0; f convex decreasing -> monotone)
    float tau = mx - 1.f;
    float S = 0.f;
    float pr[32];
    for (int it = 0; it < NNEWT; ++it) {
        float s0=0.f,s1=0.f,s2=0.f,s3=0.f;
        float g0=0.f,g1=0.f,g2=0.f,g3=0.f;
        #pragma unroll
        for (int e = 0; e < 32; e += 4) {
            #pragma unroll
            for (int k = 0; k < 4; ++k) {
                float z  = Xs[e + k] - tau;
                float zc = fmaxf(z, 0.f);
                float dp = hw_exp2(im1 * hw_log2(zc));   // zc^(inv-1); exp2(-inf)=0
                dp = (zc > 0.f) ? dp : 0.f;              // guards im1==0 NaN case
                float p  = dp * zc;                      // zc^inv
                pr[e + k] = p;
                if (k == 0) { s0 += p; g0 += dp; }
                else if (k == 1) { s1 += p; g1 += dp; }
                else if (k == 2) { s2 += p; g2 += dp; }
                else { s3 += p; g3 += dp; }
            }
        }
        S        = rsum16((s0 + s1) + (s2 + s3));
        float Sp = rsum16((g0 + g1) + (g2 + g3));
        tau += (S - 1.f) / (inv * Sp);   // last update unused by design
    }

    float rn = 1.f / S;                  // S and pr are from the same (final) eval
    #pragma unroll
    for (int e = 0; e < 32; ++e) SL[row][e * 16 + lp] = pr[e] * rn;
    // intra-wave only -> no barrier

    // ---- phase D: PV straight from global X; att[d=lane] per row ----
    float att0 = 0.f, att1 = 0.f, att2 = 0.f, att3 = 0.f;
    const float* xp = X + (size_t)(b << 9) * 512 + (h << 6) + lane;
    #pragma unroll 4
    for (int j4 = 0; j4 < 128; ++j4) {
        float4 p0 = *(const float4*)&SL[w*4+0][j4*4];
        float4 p1 = *(const float4*)&SL[w*4+1][j4*4];
        float4 p2 = *(const float4*)&SL[w*4+2][j4*4];
        float4 p3 = *(const float4*)&SL[w*4+3][j4*4];
        #pragma unroll
        for (int qq = 0; qq < 4; ++qq) {
            float xv = xp[(size_t)(j4*4+qq) * 512];
            float pq0 = qq==0?p0.x:qq==1?p0.y:qq==2?p0.z:p0.w;
            float pq1 = qq==0?p1.x:qq==1?p1.y:qq==2?p1.z:p1.w;
            float pq2 = qq==0?p2.x:qq==1?p2.y:qq==2?p2.z:p2.w;
            float pq3 = qq==0?p3.x:qq==1?p3.y:qq==2?p3.z:p3.w;
            att0 = fmaf(pq0, xv, att0);
            att1 = fmaf(pq1, xv, att1);
            att2 = fmaf(pq2, xv, att2);
            att3 = fmaf(pq3, xv, att3);
        }
    }

    {
        int ibase = rg * 16 + w * 4;
        ATT[((size_t)(b << 9) + ibase + 0) * 512 + (h << 6) + lane] = att0;
        ATT[((size_t)(b << 9) + ibase + 1) * 512 + (h << 6) + lane] = att1;
        ATT[((size_t)(b << 9) + ibase + 2) * 512 + (h << 6) + lane] = att2;
        ATT[((size_t)(b << 9) + ibase + 3) * 512 + (h << 6) + lane] = att3;
    }
}

// ---------------- LayerNorm + scatter ----------------
__global__ __launch_bounds__(256) void ln_kernel(const float* __restrict__ Cb,
                                                 const float* __restrict__ g,
                                                 const float* __restrict__ beta,
                                                 float* __restrict__ out)
{
    const int w = threadIdx.x >> 6, lane = threadIdx.x & 63;
    const int row = blockIdx.x * 4 + w;
    const int b = row >> 9, l = row & 511;
    const float* x = Cb + (size_t)row * 512;

    float v[8], s = 0.f;
    #pragma unroll
    for (int k = 0; k < 8; ++k) { v[k] = x[k * 64 + lane]; s += v[k]; }
    s = wsum(s);
    float mu = s * (1.f / 512.f);
    float q = 0.f;
    #pragma unroll
    for (int k = 0; k < 8; ++k) { float d = v[k] - mu; q = fmaf(d, d, q); }
    q = wsum(q);
    float rs = rsqrtf(q * (1.f / 512.f) + 1e-12f);

    float* dst = (l < 511) ? (out + (size_t)(b * 511 + l) * 512)
                           : (out + (size_t)16 * 511 * 512 + (size_t)b * 512);
    #pragma unroll
    for (int k = 0; k < 8; ++k) {
        int d = k * 64 + lane;
        dst[d] = (v[k] - mu) * rs * g[d] + beta[d];
    }
}

// ---------------- launch ----------------
extern "C" void kernel_launch(void* const* d_in, const int* in_sizes, int n_in,
                              void* d_out, int out_size, void* d_ws, size_t ws_size,
                              hipStream_t stream)
{
    const float* X    = (const float*)d_in[0];
    const float* mask = (const float*)d_in[1];
    const float* Wq   = (const float*)d_in[2];
    const float* bq   = (const float*)d_in[3];
    const float* W1   = (const float*)d_in[4];
    const float* b1   = (const float*)d_in[5];
    const float* W2   = (const float*)d_in[6];
    const float* b2   = (const float*)d_in[7];
    const float* lng  = (const float*)d_in[8];
    const float* lnb  = (const float*)d_in[9];
    const float* Wa   = (const float*)d_in[10];
    const float* ba   = (const float*)d_in[11];
    float* out = (float*)d_out;
    float* ws  = (float*)d_ws;

    const size_t NE = (size_t)BB * LL * DD;      // 4194304
    if (ws_size < (3 * NE + 256) * sizeof(float)) return;

    float* Qb   = ws;
    float* Kt   = ws + NE;
    float* ATT  = ws + 2 * NE;
    float* am1v = ws + 3 * NE;
    float* invv = am1v + 128;
    float* Hh = Kt;
    float* Cb = Qb;

    const int M = BB * LL;       // 8192

    gemm_bias_kernel<1, false><<<dim3(DD / BN, M / BM), 256, 0, stream>>>(
        X, Wq, bq, nullptr, Qb, M, DD, DD);
    transpose_kt<<<(int)(NE / 256), 256, 0, stream>>>(X, Kt);
    alpha_kernel<<<1, 128, 0, stream>>>(Qb, Wa, ba, am1v, invv);
    attn_kernel<<<BB * HH * LL / 16, 256, 0, stream>>>(Qb, X, Kt, mask, am1v, invv, ATT);
    gemm_bias_kernel<1, false><<<dim3(DD / BN, M / BM), 256, 0, stream>>>(
        ATT, W1, b1, nullptr, Hh, M, DD, DD);
    gemm_bias_kernel<0, true><<<dim3(DD / BN, M / BM), 256, 0, stream>>>(
        Hh, W2, b2, ATT, Cb, M, DD, DD);
    ln_kernel<<<M / 4, 256, 0, stream>>>(Cb, lng, lnb, out);
}

// Round 5
// 403.614 us; speedup vs baseline: 2.5640x; 1.3269x over previous
//
#include <hip/hip_runtime.h>
#include <math.h>

#define BB   16
#define LL   512
#define DD   512
#define HH   8
#define HDIM 64
#define NNEWT 12

typedef unsigned short ushort_t;
typedef __attribute__((ext_vector_type(8))) short short8;
typedef __attribute__((ext_vector_type(4))) float f32x4;

// raw single-instruction transcendentals
__device__ __forceinline__ float hw_log2(float x) { return __builtin_amdgcn_logf(x); }
__device__ __forceinline__ float hw_exp2(float x) { return __builtin_amdgcn_exp2f(x); }

__device__ __forceinline__ ushort_t f2b(float f) {
    unsigned u = __builtin_bit_cast(unsigned, f);
    unsigned r = u + 0x7FFFu + ((u >> 16) & 1u);     // RNE
    return (ushort_t)(r >> 16);
}

// ---------------- wave-wide reduction (64 lanes) for ln ----------------
__device__ __forceinline__ float wsum(float v) {
    v += __shfl_xor(v, 1);  v += __shfl_xor(v, 2);  v += __shfl_xor(v, 4);
    v += __shfl_xor(v, 8);  v += __shfl_xor(v, 16); v += __shfl_xor(v, 32);
    return v;
}

// ---------------- DPP 16-lane-group butterflies ----------------
template<int CTRL>
__device__ __forceinline__ float dpp_mov(float v) {
    return __builtin_bit_cast(float, __builtin_amdgcn_update_dpp(
        0, __builtin_bit_cast(int, v), CTRL, 0xf, 0xf, true));
}
__device__ __forceinline__ float rsum16(float v) {
    v += dpp_mov<0xB1>(v);
    v += dpp_mov<0x4E>(v);
    v += dpp_mov<0x141>(v);
    v += dpp_mov<0x140>(v);
    return v;
}
__device__ __forceinline__ float rmax16(float v) {
    v = fmaxf(v, dpp_mov<0xB1>(v));
    v = fmaxf(v, dpp_mov<0x4E>(v));
    v = fmaxf(v, dpp_mov<0x141>(v));
    v = fmaxf(v, dpp_mov<0x140>(v));
    return v;
}

// ---------------- fp32 -> bf16 conversion (memory-bound) ----------------
__global__ __launch_bounds__(256) void conv_f2b(const float* __restrict__ in,
                                                ushort_t* __restrict__ out)
{
    int i = (blockIdx.x * 256 + threadIdx.x) * 4;
    float4 v = *(const float4*)&in[i];
    ushort4 o;
    o.x = f2b(v.x); o.y = f2b(v.y); o.z = f2b(v.z); o.w = f2b(v.w);
    *(ushort4*)&out[i] = o;
}

// ---------------- bf16 MFMA GEMM: C = act(A @ W^T + bias) [+ resid] ----------------
// A: [M,K] bf16 row-major, W: [N,K] bf16 row-major. M=8192,N=512,K=512.
// 64x64 block tile, BK=64, 4 waves (2x2), per-wave 32x32 (2x2 fragments).
// LDS tiles staged via global_load_lds w=16 with XOR swizzle (granule ^= row&7)
// applied on BOTH the global source column and the ds_read address (rule #21).
__device__ __forceinline__ void gload16(const void* g, void* l) {
    __builtin_amdgcn_global_load_lds(
        (const __attribute__((address_space(1))) unsigned*)g,
        (__attribute__((address_space(3))) unsigned*)l, 16, 0, 0);
}

template<int ACT, bool RES, bool OBF16>
__global__ __launch_bounds__(256) void gemm_mfma(
    const ushort_t* __restrict__ A, const ushort_t* __restrict__ W,
    const float* __restrict__ bias, const float* __restrict__ resid,
    void* __restrict__ Cout, int M, int N, int K)
{
    __shared__ ushort_t Asw[64 * 64];   // [row][64], 128B rows, swizzled granules
    __shared__ ushort_t Bsw[64 * 64];

    const int tid = threadIdx.x;
    const int w = tid >> 6, lane = tid & 63;
    const int wm = w >> 1, wn = w & 1;
    const int bm = blockIdx.y * 64, bn = blockIdx.x * 64;

    const int l3 = lane >> 3, l7 = lane & 7;
    const int srcg = l7 ^ l3;               // pre-swizzled source granule
    const int l15 = lane & 15, hi = lane >> 4;

    f32x4 acc[2][2] = {};

    for (int kt = 0; kt < K; kt += 64) {
        #pragma unroll
        for (int u = 0; u < 2; ++u) {
            int q = w * 2 + u;              // 8-row group 0..7
            gload16(&A[(size_t)(bm + q * 8 + l3) * K + kt + srcg * 8], &Asw[q * 512]);
            gload16(&W[(size_t)(bn + q * 8 + l3) * K + kt + srcg * 8], &Bsw[q * 512]);
        }
        __syncthreads();

        #pragma unroll
        for (int kk = 0; kk < 2; ++kk) {
            const int s = (kk * 4 + hi) ^ l7;   // swizzled read granule (R&7 == l7)
            short8 a[2], b[2];
            #pragma unroll
            for (int f = 0; f < 2; ++f) {
                a[f] = *(const short8*)&Asw[(wm * 32 + f * 16 + l15) * 64 + s * 8];
                b[f] = *(const short8*)&Bsw[(wn * 32 + f * 16 + l15) * 64 + s * 8];
            }
            #pragma unroll
            for (int i = 0; i < 2; ++i)
                #pragma unroll
                for (int j = 0; j < 2; ++j)
                    acc[i][j] = __builtin_amdgcn_mfma_f32_16x16x32_bf16(
                        a[i], b[j], acc[i][j], 0, 0, 0);
        }
        __syncthreads();
    }

    // epilogue: D row=(lane>>4)*4+r, col=lane&15
    #pragma unroll
    for (int i = 0; i < 2; ++i) {
        #pragma unroll
        for (int j = 0; j < 2; ++j) {
            #pragma unroll
            for (int r = 0; r < 4; ++r) {
                const int m = bm + wm * 32 + i * 16 + hi * 4 + r;
                const int n = bn + wn * 32 + j * 16 + l15;
                float v = acc[i][j][r] + bias[n];
                if (ACT == 1) v = fmaxf(v, 0.f);
                if (RES) v += resid[(size_t)m * N + n];
                if (OBF16) ((ushort_t*)Cout)[(size_t)m * N + n] = f2b(v);
                else       ((float*)Cout)[(size_t)m * N + n] = v;
            }
        }
    }
}

// ---------------- Kt[b,h][d][j] = X[b,j,h*64+d] ----------------
__global__ __launch_bounds__(256) void transpose_kt(const float* __restrict__ X,
                                                    float* __restrict__ Kt)
{
    int o = blockIdx.x * 256 + threadIdx.x;
    int j = o & 511;
    int d = (o >> 9) & 63;
    int h = (o >> 15) & 7;
    int b = o >> 18;
    Kt[o] = X[((b << 9) + j) * 512 + h * 64 + d];
}

// ---------------- alpha per (b,h) ----------------
__global__ void alpha_kernel(const float* __restrict__ Q, const float* __restrict__ Wa,
                             const float* __restrict__ ba,
                             float* __restrict__ am1v, float* __restrict__ invv)
{
    int t = threadIdx.x;
    if (t >= BB * HH) return;
    int b = t >> 3, h = t & 7;
    float acc = 0.f;
    #pragma unroll
    for (int d = 0; d < HDIM; ++d)
        acc = fmaf(Q[((b << 9) + 511) * 512 + h * 64 + d], Wa[d], acc);
    acc += ba[0];
    float sig = 1.f / (1.f + expf(-acc));
    float alpha = sig + 1.f;
    const float amin = 1.f + 1e-5f;
    if (alpha < amin) alpha = amin;
    float am1 = alpha - 1.f;
    am1v[t] = am1;
    invv[t] = 1.f / am1;
}

// ---------------- fused attention v4 (spill-free Newton) ----------------
#define SLS 520
__global__ __launch_bounds__(256, 4) void attn_kernel(
    const float* __restrict__ Q, const float* __restrict__ X, const float* __restrict__ Kt,
    const float* __restrict__ mask, const float* __restrict__ am1v,
    const float* __restrict__ invv, float* __restrict__ ATT)
{
    __shared__ float qs[16][68];
    __shared__ float SL[16][SLS];      // scores -> unnormalized p; [row][512] = 1/S

    const int bid = ((blockIdx.x & 7) << 9) + (blockIdx.x >> 3);   // XCD swizzle
    const int bh = bid >> 5;
    const int rg = bid & 31;
    const int b = bh >> 3, h = bh & 7;
    const int tid = threadIdx.x;
    const int w = tid >> 6, lane = tid & 63;

    const float am1 = am1v[bh];
    const float inv = invv[bh];
    const float im1 = inv - 1.f;
    const float* KtBH = Kt + (size_t)bh * (64 * 512);

    // ---- phase A: stage q rows ----
    #pragma unroll
    for (int it = 0; it < 4; ++it) {
        int idx = tid + it * 256;
        int rr = idx >> 6, d = idx & 63;
        qs[rr][d] = Q[((b << 9) + rg * 16 + rr) * 512 + (h << 6) + d];
    }
    __syncthreads();   // the only barrier

    // ---- phase B: scores straight from global Kt; 2 chunks x 256 j ----
    #pragma unroll
    for (int c = 0; c < 2; ++c) {
        float acc[4][4] = {{0,0,0,0},{0,0,0,0},{0,0,0,0},{0,0,0,0}};
        const float* kp = KtBH + c * 256 + 4 * lane;
        #pragma unroll
        for (int d4 = 0; d4 < 16; ++d4) {
            float4 qv0 = *(const float4*)&qs[w*4+0][d4*4];
            float4 qv1 = *(const float4*)&qs[w*4+1][d4*4];
            float4 qv2 = *(const float4*)&qs[w*4+2][d4*4];
            float4 qv3 = *(const float4*)&qs[w*4+3][d4*4];
            #pragma unroll
            for (int dd = 0; dd < 4; ++dd) {
                float4 kv = *(const float4*)&kp[(size_t)(d4*4+dd) * 512];
                float q0 = dd==0?qv0.x:dd==1?qv0.y:dd==2?qv0.z:qv0.w;
                float q1 = dd==0?qv1.x:dd==1?qv1.y:dd==2?qv1.z:qv1.w;
                float q2 = dd==0?qv2.x:dd==1?qv2.y:dd==2?qv2.z:qv2.w;
                float q3 = dd==0?qv3.x:dd==1?qv3.y:dd==2?qv3.z:qv3.w;
                acc[0][0]=fmaf(q0,kv.x,acc[0][0]); acc[0][1]=fmaf(q0,kv.y,acc[0][1]);
                acc[0][2]=fmaf(q0,kv.z,acc[0][2]); acc[0][3]=fmaf(q0,kv.w,acc[0][3]);
                acc[1][0]=fmaf(q1,kv.x,acc[1][0]); acc[1][1]=fmaf(q1,kv.y,acc[1][1]);
                acc[1][2]=fmaf(q1,kv.z,acc[1][2]); acc[1][3]=fmaf(q1,kv.w,acc[1][3]);
                acc[2][0]=fmaf(q2,kv.x,acc[2][0]); acc[2][1]=fmaf(q2,kv.y,acc[2][1]);
                acc[2][2]=fmaf(q2,kv.z,acc[2][2]); acc[2][3]=fmaf(q2,kv.w,acc[2][3]);
                acc[3][0]=fmaf(q3,kv.x,acc[3][0]); acc[3][1]=fmaf(q3,kv.y,acc[3][1]);
                acc[3][2]=fmaf(q3,kv.z,acc[3][2]); acc[3][3]=fmaf(q3,kv.w,acc[3][3]);
            }
        }
        int jb = c * 256 + 4 * lane;
        *(float4*)&SL[w*4+0][jb] = make_float4(acc[0][0],acc[0][1],acc[0][2],acc[0][3]);
        *(float4*)&SL[w*4+1][jb] = make_float4(acc[1][0],acc[1][1],acc[1][2],acc[1][3]);
        *(float4*)&SL[w*4+2][jb] = make_float4(acc[2][0],acc[2][1],acc[2][2],acc[2][3]);
        *(float4*)&SL[w*4+3][jb] = make_float4(acc[3][0],acc[3][1],acc[3][2],acc[3][3]);
    }

    // ---- phase C: entmax via spill-free monotone Newton ----
    const int lp = lane & 15, g = lane >> 4;
    const int row = w * 4 + g;
    const float NEG = -__builtin_inff();

    float Xs[32];
    #pragma unroll
    for (int e = 0; e < 32; ++e) {
        int j = e * 16 + lp;
        float sv = SL[row][j];
        float mv = (j < 511) ? mask[b * 511 + j] : 0.f;  // last key always masked
        Xs[e] = (mv == 0.f) ? NEG : sv * 0.125f * am1;
    }

    float mx = Xs[0];
    #pragma unroll
    for (int e = 1; e < 32; ++e) mx = fmaxf(mx, Xs[e]);
    mx = rmax16(mx);

    float tau = mx - 1.f;          // f(tau) >= 0 here; f convex decreasing
    for (int it = 0; it < NNEWT; ++it) {
        float s0=0.f,s1=0.f,s2=0.f,s3=0.f;
        float g0=0.f,g1=0.f,g2=0.f,g3=0.f;
        #pragma unroll
        for (int e = 0; e < 32; e += 4) {
            #pragma unroll
            for (int k = 0; k < 4; ++k) {
                float z  = Xs[e + k] - tau;
                float zc = fmaxf(z, 0.f);
                float dp = hw_exp2(im1 * hw_log2(zc));   // zc^(inv-1)
                dp = (zc > 0.f) ? dp : 0.f;              // guard im1==0 NaN
                float p  = dp * zc;
                if (k == 0) { s0 += p; g0 += dp; }
                else if (k == 1) { s1 += p; g1 += dp; }
                else if (k == 2) { s2 += p; g2 += dp; }
                else { s3 += p; g3 += dp; }
            }
        }
        float S  = rsum16((s0 + s1) + (s2 + s3));
        float Sp = rsum16((g0 + g1) + (g2 + g3));
        tau += (S - 1.f) / (inv * Sp);
    }

    // final eval: write UNNORMALIZED p to SL (streaming, no pr[] array);
    // stash 1/S at SL[row][512]; PV scales its accumulators at the end.
    {
        float s0=0.f,s1=0.f,s2=0.f,s3=0.f;
        #pragma unroll
        for (int e = 0; e < 32; e += 4) {
            #pragma unroll
            for (int k = 0; k < 4; ++k) {
                float zc = fmaxf(Xs[e + k] - tau, 0.f);
                float p  = hw_exp2(inv * hw_log2(zc));   // inv>=1: exp2(-inf)=0 ok
                SL[row][(e + k) * 16 + lp] = p;
                if (k == 0) s0 += p; else if (k == 1) s1 += p;
                else if (k == 2) s2 += p; else s3 += p;
            }
        }
        float S = rsum16((s0 + s1) + (s2 + s3));
        if (lp == 0) SL[row][512] = 1.f / S;
    }

    // ---- phase D: PV straight from global X ----
    float att0 = 0.f, att1 = 0.f, att2 = 0.f, att3 = 0.f;
    const float* xp = X + (size_t)(b << 9) * 512 + (h << 6) + lane;
    #pragma unroll 4
    for (int j4 = 0; j4 < 128; ++j4) {
        float4 p0 = *(const float4*)&SL[w*4+0][j4*4];
        float4 p1 = *(const float4*)&SL[w*4+1][j4*4];
        float4 p2 = *(const float4*)&SL[w*4+2][j4*4];
        float4 p3 = *(const float4*)&SL[w*4+3][j4*4];
        #pragma unroll
        for (int qq = 0; qq < 4; ++qq) {
            float xv = xp[(size_t)(j4*4+qq) * 512];
            float pq0 = qq==0?p0.x:qq==1?p0.y:qq==2?p0.z:p0.w;
            float pq1 = qq==0?p1.x:qq==1?p1.y:qq==2?p1.z:p1.w;
            float pq2 = qq==0?p2.x:qq==1?p2.y:qq==2?p2.z:p2.w;
            float pq3 = qq==0?p3.x:qq==1?p3.y:qq==2?p3.z:p3.w;
            att0 = fmaf(pq0, xv, att0);
            att1 = fmaf(pq1, xv, att1);
            att2 = fmaf(pq2, xv, att2);
            att3 = fmaf(pq3, xv, att3);
        }
    }
    att0 *= SL[w*4+0][512];
    att1 *= SL[w*4+1][512];
    att2 *= SL[w*4+2][512];
    att3 *= SL[w*4+3][512];

    {
        int ibase = rg * 16 + w * 4;
        ATT[((size_t)(b << 9) + ibase + 0) * 512 + (h << 6) + lane] = att0;
        ATT[((size_t)(b << 9) + ibase + 1) * 512 + (h << 6) + lane] = att1;
        ATT[((size_t)(b << 9) + ibase + 2) * 512 + (h << 6) + lane] = att2;
        ATT[((size_t)(b << 9) + ibase + 3) * 512 + (h << 6) + lane] = att3;
    }
}

// ---------------- LayerNorm + scatter ----------------
__global__ __launch_bounds__(256) void ln_kernel(const float* __restrict__ Cb,
                                                 const float* __restrict__ g,
                                                 const float* __restrict__ beta,
                                                 float* __restrict__ out)
{
    const int w = threadIdx.x >> 6, lane = threadIdx.x & 63;
    const int row = blockIdx.x * 4 + w;
    const int b = row >> 9, l = row & 511;
    const float* x = Cb + (size_t)row * 512;

    float v[8], s = 0.f;
    #pragma unroll
    for (int k = 0; k < 8; ++k) { v[k] = x[k * 64 + lane]; s += v[k]; }
    s = wsum(s);
    float mu = s * (1.f / 512.f);
    float q = 0.f;
    #pragma unroll
    for (int k = 0; k < 8; ++k) { float d = v[k] - mu; q = fmaf(d, d, q); }
    q = wsum(q);
    float rs = rsqrtf(q * (1.f / 512.f) + 1e-12f);

    float* dst = (l < 511) ? (out + (size_t)(b * 511 + l) * 512)
                           : (out + (size_t)16 * 511 * 512 + (size_t)b * 512);
    #pragma unroll
    for (int k = 0; k < 8; ++k) {
        int d = k * 64 + lane;
        dst[d] = (v[k] - mu) * rs * g[d] + beta[d];
    }
}

// ---------------- launch ----------------
extern "C" void kernel_launch(void* const* d_in, const int* in_sizes, int n_in,
                              void* d_out, int out_size, void* d_ws, size_t ws_size,
                              hipStream_t stream)
{
    const float* X    = (const float*)d_in[0];
    const float* mask = (const float*)d_in[1];
    const float* Wq   = (const float*)d_in[2];
    const float* bq   = (const float*)d_in[3];
    const float* W1   = (const float*)d_in[4];
    const float* b1   = (const float*)d_in[5];
    const float* W2   = (const float*)d_in[6];
    const float* b2   = (const float*)d_in[7];
    const float* lng  = (const float*)d_in[8];
    const float* lnb  = (const float*)d_in[9];
    const float* Wa   = (const float*)d_in[10];
    const float* ba   = (const float*)d_in[11];
    float* out = (float*)d_out;
    float* ws  = (float*)d_ws;

    const size_t NE = (size_t)BB * LL * DD;      // 4194304
    const size_t WN = (size_t)DD * DD;           // 262144
    if (ws_size < (3 * NE + 256) * sizeof(float) + 3 * WN * sizeof(ushort_t)) return;

    float* Qb   = ws;                 // fp32 q-proj out; later bf16 ATTb/Hhb pool
    float* Kt   = ws + NE;            // fp32 K^T; later fp32 Cb
    float* ATT  = ws + 2 * NE;        // first bf16 Xb; then fp32 attn out
    float* am1v = ws + 3 * NE;
    float* invv = am1v + 128;
    ushort_t* Wqb = (ushort_t*)(am1v + 256);
    ushort_t* W1b = Wqb + WN;
    ushort_t* W2b = W1b + WN;
    ushort_t* Xb   = (ushort_t*)ATT;       // dead before attn writes ATT
    ushort_t* ATTb = (ushort_t*)Qb;        // Qb dead after attn
    ushort_t* Hhb  = (ushort_t*)Qb + NE;   // second half of Qb slot
    float* Cb = Kt;                        // Kt dead after attn

    const int M = BB * LL;       // 8192

    conv_f2b<<<(int)(NE / 1024), 256, 0, stream>>>(X, Xb);
    conv_f2b<<<(int)(WN / 1024), 256, 0, stream>>>(Wq, Wqb);
    gemm_mfma<1, false, false><<<dim3(DD / 64, M / 64), 256, 0, stream>>>(
        Xb, Wqb, bq, nullptr, Qb, M, DD, DD);
    transpose_kt<<<(int)(NE / 256), 256, 0, stream>>>(X, Kt);
    alpha_kernel<<<1, 128, 0, stream>>>(Qb, Wa, ba, am1v, invv);
    attn_kernel<<<BB * HH * LL / 16, 256, 0, stream>>>(Qb, X, Kt, mask, am1v, invv, ATT);
    conv_f2b<<<(int)(NE / 1024), 256, 0, stream>>>(ATT, ATTb);
    conv_f2b<<<(int)(WN / 1024), 256, 0, stream>>>(W1, W1b);
    gemm_mfma<1, false, true><<<dim3(DD / 64, M / 64), 256, 0, stream>>>(
        ATTb, W1b, b1, nullptr, Hhb, M, DD, DD);
    conv_f2b<<<(int)(WN / 1024), 256, 0, stream>>>(W2, W2b);
    gemm_mfma<0, true, false><<<dim3(DD / 64, M / 64), 256, 0, stream>>>(
        Hhb, W2b, b2, ATT, Cb, M, DD, DD);
    ln_kernel<<<M / 4, 256, 0, stream>>>(Cb, lng, lnb, out);
}

// Round 6
// 398.537 us; speedup vs baseline: 2.5967x; 1.0127x over previous
//
#include <hip/hip_runtime.h>
#include <math.h>

#define BB   16
#define LL   512
#define DD   512
#define HH   8
#define HDIM 64
#define NNEWT 12

typedef unsigned short ushort_t;
typedef __attribute__((ext_vector_type(8))) short short8;
typedef __attribute__((ext_vector_type(4))) float f32x4;

// raw single-instruction transcendentals
__device__ __forceinline__ float hw_log2(float x) { return __builtin_amdgcn_logf(x); }
__device__ __forceinline__ float hw_exp2(float x) { return __builtin_amdgcn_exp2f(x); }

__device__ __forceinline__ ushort_t f2b(float f) {
    unsigned u = __builtin_bit_cast(unsigned, f);
    unsigned r = u + 0x7FFFu + ((u >> 16) & 1u);     // RNE
    return (ushort_t)(r >> 16);
}

// ---------------- wave-wide reduction (64 lanes) for ln ----------------
__device__ __forceinline__ float wsum(float v) {
    v += __shfl_xor(v, 1);  v += __shfl_xor(v, 2);  v += __shfl_xor(v, 4);
    v += __shfl_xor(v, 8);  v += __shfl_xor(v, 16); v += __shfl_xor(v, 32);
    return v;
}

// ---------------- DPP 16-lane-group butterflies ----------------
template<int CTRL>
__device__ __forceinline__ float dpp_mov(float v) {
    return __builtin_bit_cast(float, __builtin_amdgcn_update_dpp(
        0, __builtin_bit_cast(int, v), CTRL, 0xf, 0xf, true));
}
__device__ __forceinline__ float rsum16(float v) {
    v += dpp_mov<0xB1>(v);
    v += dpp_mov<0x4E>(v);
    v += dpp_mov<0x141>(v);
    v += dpp_mov<0x140>(v);
    return v;
}
__device__ __forceinline__ float rmax16(float v) {
    v = fmaxf(v, dpp_mov<0xB1>(v));
    v = fmaxf(v, dpp_mov<0x4E>(v));
    v = fmaxf(v, dpp_mov<0x141>(v));
    v = fmaxf(v, dpp_mov<0x140>(v));
    return v;
}

// ---------------- fp32 -> bf16 conversion (memory-bound) ----------------
__global__ __launch_bounds__(256) void conv_f2b(const float* __restrict__ in,
                                                ushort_t* __restrict__ out)
{
    int i = (blockIdx.x * 256 + threadIdx.x) * 4;
    float4 v = *(const float4*)&in[i];
    ushort4 o;
    o.x = f2b(v.x); o.y = f2b(v.y); o.z = f2b(v.z); o.w = f2b(v.w);
    *(ushort4*)&out[i] = o;
}

// ---------------- bf16 MFMA GEMM: C = act(A @ W^T + bias) [+ resid] ----------------
__device__ __forceinline__ void gload16(const void* g, void* l) {
    __builtin_amdgcn_global_load_lds(
        (const __attribute__((address_space(1))) unsigned*)g,
        (__attribute__((address_space(3))) unsigned*)l, 16, 0, 0);
}

template<int ACT, bool RES, bool OBF16>
__global__ __launch_bounds__(256) void gemm_mfma(
    const ushort_t* __restrict__ A, const ushort_t* __restrict__ W,
    const float* __restrict__ bias, const float* __restrict__ resid,
    void* __restrict__ Cout, int M, int N, int K)
{
    __shared__ ushort_t Asw[64 * 64];
    __shared__ ushort_t Bsw[64 * 64];

    const int tid = threadIdx.x;
    const int w = tid >> 6, lane = tid & 63;
    const int wm = w >> 1, wn = w & 1;
    const int bm = blockIdx.y * 64, bn = blockIdx.x * 64;

    const int l3 = lane >> 3, l7 = lane & 7;
    const int srcg = l7 ^ l3;               // pre-swizzled source granule
    const int l15 = lane & 15, hi = lane >> 4;

    f32x4 acc[2][2] = {};

    for (int kt = 0; kt < K; kt += 64) {
        #pragma unroll
        for (int u = 0; u < 2; ++u) {
            int q = w * 2 + u;
            gload16(&A[(size_t)(bm + q * 8 + l3) * K + kt + srcg * 8], &Asw[q * 512]);
            gload16(&W[(size_t)(bn + q * 8 + l3) * K + kt + srcg * 8], &Bsw[q * 512]);
        }
        __syncthreads();

        #pragma unroll
        for (int kk = 0; kk < 2; ++kk) {
            const int s = (kk * 4 + hi) ^ l7;   // swizzled read granule
            short8 a[2], b[2];
            #pragma unroll
            for (int f = 0; f < 2; ++f) {
                a[f] = *(const short8*)&Asw[(wm * 32 + f * 16 + l15) * 64 + s * 8];
                b[f] = *(const short8*)&Bsw[(wn * 32 + f * 16 + l15) * 64 + s * 8];
            }
            #pragma unroll
            for (int i = 0; i < 2; ++i)
                #pragma unroll
                for (int j = 0; j < 2; ++j)
                    acc[i][j] = __builtin_amdgcn_mfma_f32_16x16x32_bf16(
                        a[i], b[j], acc[i][j], 0, 0, 0);
        }
        __syncthreads();
    }

    #pragma unroll
    for (int i = 0; i < 2; ++i) {
        #pragma unroll
        for (int j = 0; j < 2; ++j) {
            #pragma unroll
            for (int r = 0; r < 4; ++r) {
                const int m = bm + wm * 32 + i * 16 + hi * 4 + r;
                const int n = bn + wn * 32 + j * 16 + l15;
                float v = acc[i][j][r] + bias[n];
                if (ACT == 1) v = fmaxf(v, 0.f);
                if (RES) v += resid[(size_t)m * N + n];
                if (OBF16) ((ushort_t*)Cout)[(size_t)m * N + n] = f2b(v);
                else       ((float*)Cout)[(size_t)m * N + n] = v;
            }
        }
    }
}

// ---------------- Kt[b,h][d][j] = X[b,j,h*64+d] ----------------
__global__ __launch_bounds__(256) void transpose_kt(const float* __restrict__ X,
                                                    float* __restrict__ Kt)
{
    int o = blockIdx.x * 256 + threadIdx.x;
    int j = o & 511;
    int d = (o >> 9) & 63;
    int h = (o >> 15) & 7;
    int b = o >> 18;
    Kt[o] = X[((b << 9) + j) * 512 + h * 64 + d];
}

// ---------------- alpha per (b,h) ----------------
__global__ void alpha_kernel(const float* __restrict__ Q, const float* __restrict__ Wa,
                             const float* __restrict__ ba,
                             float* __restrict__ am1v, float* __restrict__ invv)
{
    int t = threadIdx.x;
    if (t >= BB * HH) return;
    int b = t >> 3, h = t & 7;
    float acc = 0.f;
    #pragma unroll
    for (int d = 0; d < HDIM; ++d)
        acc = fmaf(Q[((b << 9) + 511) * 512 + h * 64 + d], Wa[d], acc);
    acc += ba[0];
    float sig = 1.f / (1.f + expf(-acc));
    float alpha = sig + 1.f;
    const float amin = 1.f + 1e-5f;
    if (alpha < amin) alpha = amin;
    float am1 = alpha - 1.f;
    am1v[t] = am1;
    invv[t] = 1.f / am1;
}

// ---------------- fused attention v5 (LDS-resident scores, no per-lane array) ----------------
#define SLS 520
__global__ __launch_bounds__(256, 4) void attn_kernel(
    const float* __restrict__ Q, const float* __restrict__ X, const float* __restrict__ Kt,
    const float* __restrict__ mask, const float* __restrict__ am1v,
    const float* __restrict__ invv, float* __restrict__ ATT)
{
    __shared__ float qs[16][68];
    __shared__ float SL[16][SLS];      // scores -> masked Xs -> unnorm p; [row][512]=1/S

    const int bid = ((blockIdx.x & 7) << 9) + (blockIdx.x >> 3);   // XCD swizzle
    const int bh = bid >> 5;
    const int rg = bid & 31;
    const int b = bh >> 3, h = bh & 7;
    const int tid = threadIdx.x;
    const int w = tid >> 6, lane = tid & 63;

    const float am1 = am1v[bh];
    const float inv = invv[bh];
    const float im1 = inv - 1.f;
    const float* KtBH = Kt + (size_t)bh * (64 * 512);

    // ---- phase A: stage q rows ----
    #pragma unroll
    for (int it = 0; it < 4; ++it) {
        int idx = tid + it * 256;
        int rr = idx >> 6, d = idx & 63;
        qs[rr][d] = Q[((b << 9) + rg * 16 + rr) * 512 + (h << 6) + d];
    }
    __syncthreads();   // the only barrier

    // ---- phase B: scores straight from global Kt; 2 chunks x 256 j ----
    #pragma unroll
    for (int c = 0; c < 2; ++c) {
        float acc[4][4] = {{0,0,0,0},{0,0,0,0},{0,0,0,0},{0,0,0,0}};
        const float* kp = KtBH + c * 256 + 4 * lane;
        #pragma unroll
        for (int d4 = 0; d4 < 16; ++d4) {
            float4 qv0 = *(const float4*)&qs[w*4+0][d4*4];
            float4 qv1 = *(const float4*)&qs[w*4+1][d4*4];
            float4 qv2 = *(const float4*)&qs[w*4+2][d4*4];
            float4 qv3 = *(const float4*)&qs[w*4+3][d4*4];
            #pragma unroll
            for (int dd = 0; dd < 4; ++dd) {
                float4 kv = *(const float4*)&kp[(size_t)(d4*4+dd) * 512];
                float q0 = dd==0?qv0.x:dd==1?qv0.y:dd==2?qv0.z:qv0.w;
                float q1 = dd==0?qv1.x:dd==1?qv1.y:dd==2?qv1.z:qv1.w;
                float q2 = dd==0?qv2.x:dd==1?qv2.y:dd==2?qv2.z:qv2.w;
                float q3 = dd==0?qv3.x:dd==1?qv3.y:dd==2?qv3.z:qv3.w;
                acc[0][0]=fmaf(q0,kv.x,acc[0][0]); acc[0][1]=fmaf(q0,kv.y,acc[0][1]);
                acc[0][2]=fmaf(q0,kv.z,acc[0][2]); acc[0][3]=fmaf(q0,kv.w,acc[0][3]);
                acc[1][0]=fmaf(q1,kv.x,acc[1][0]); acc[1][1]=fmaf(q1,kv.y,acc[1][1]);
                acc[1][2]=fmaf(q1,kv.z,acc[1][2]); acc[1][3]=fmaf(q1,kv.w,acc[1][3]);
                acc[2][0]=fmaf(q2,kv.x,acc[2][0]); acc[2][1]=fmaf(q2,kv.y,acc[2][1]);
                acc[2][2]=fmaf(q2,kv.z,acc[2][2]); acc[2][3]=fmaf(q2,kv.w,acc[2][3]);
                acc[3][0]=fmaf(q3,kv.x,acc[3][0]); acc[3][1]=fmaf(q3,kv.y,acc[3][1]);
                acc[3][2]=fmaf(q3,kv.z,acc[3][2]); acc[3][3]=fmaf(q3,kv.w,acc[3][3]);
            }
        }
        int jb = c * 256 + 4 * lane;
        *(float4*)&SL[w*4+0][jb] = make_float4(acc[0][0],acc[0][1],acc[0][2],acc[0][3]);
        *(float4*)&SL[w*4+1][jb] = make_float4(acc[1][0],acc[1][1],acc[1][2],acc[1][3]);
        *(float4*)&SL[w*4+2][jb] = make_float4(acc[2][0],acc[2][1],acc[2][2],acc[2][3]);
        *(float4*)&SL[w*4+3][jb] = make_float4(acc[3][0],acc[3][1],acc[3][2],acc[3][3]);
    }
    // intra-wave LDS dependency only -> no barrier

    // ---- phase C: entmax Newton; scores stay in LDS (no per-lane array) ----
    const int lp = lane & 15, g = lane >> 4;
    const int row = w * 4 + g;
    const float NEG = -__builtin_inff();

    // C1: mask + scale in place, find row max. Bank pattern: row stride 520
    // => the 4 groups sit at bank offsets {0,8,16,24}; 2 lanes/bank = free.
    float mx = NEG;
    #pragma unroll
    for (int e = 0; e < 32; ++e) {
        int j = e * 16 + lp;
        float sv = SL[row][j];
        float mv = (j < 511) ? mask[b * 511 + j] : 0.f;  // last key always masked
        float xs = (mv == 0.f) ? NEG : sv * 0.125f * am1;
        SL[row][j] = xs;
        mx = fmaxf(mx, xs);
    }
    mx = rmax16(mx);

    // C2: monotone Newton from tau_lo = mx - 1 (f>=0 there, convex decreasing)
    float tau = mx - 1.f;
    for (int it = 0; it < NNEWT; ++it) {
        float s0=0.f,s1=0.f,s2=0.f,s3=0.f;
        float g0=0.f,g1=0.f,g2=0.f,g3=0.f;
        #pragma unroll
        for (int e = 0; e < 32; e += 4) {
            #pragma unroll
            for (int k = 0; k < 4; ++k) {
                float z  = SL[row][(e + k) * 16 + lp] - tau;
                float zc = fmaxf(z, 0.f);
                float dp = hw_exp2(im1 * hw_log2(zc));   // zc^(inv-1)
                dp = (zc > 0.f) ? dp : 0.f;              // guard im1==0 NaN
                float p  = dp * zc;
                if (k == 0) { s0 += p; g0 += dp; }
                else if (k == 1) { s1 += p; g1 += dp; }
                else if (k == 2) { s2 += p; g2 += dp; }
                else { s3 += p; g3 += dp; }
            }
        }
        float S  = rsum16((s0 + s1) + (s2 + s3));
        float Sp = rsum16((g0 + g1) + (g2 + g3));
        tau += (S - 1.f) / (inv * Sp);
    }

    // C3: final eval -> unnormalized p in place; 1/S at SL[row][512]
    {
        float s0=0.f,s1=0.f,s2=0.f,s3=0.f;
        #pragma unroll
        for (int e = 0; e < 32; e += 4) {
            #pragma unroll
            for (int k = 0; k < 4; ++k) {
                int j = (e + k) * 16 + lp;
                float zc = fmaxf(SL[row][j] - tau, 0.f);
                float p  = hw_exp2(inv * hw_log2(zc));   // inv>=1: exp2(-inf)=0
                SL[row][j] = p;
                if (k == 0) s0 += p; else if (k == 1) s1 += p;
                else if (k == 2) s2 += p; else s3 += p;
            }
        }
        float S = rsum16((s0 + s1) + (s2 + s3));
        if (lp == 0) SL[row][512] = 1.f / S;
    }
    // intra-wave only -> no barrier

    // ---- phase D: PV straight from global X ----
    float att0 = 0.f, att1 = 0.f, att2 = 0.f, att3 = 0.f;
    const float* xp = X + (size_t)(b << 9) * 512 + (h << 6) + lane;
    #pragma unroll 4
    for (int j4 = 0; j4 < 128; ++j4) {
        float4 p0 = *(const float4*)&SL[w*4+0][j4*4];
        float4 p1 = *(const float4*)&SL[w*4+1][j4*4];
        float4 p2 = *(const float4*)&SL[w*4+2][j4*4];
        float4 p3 = *(const float4*)&SL[w*4+3][j4*4];
        #pragma unroll
        for (int qq = 0; qq < 4; ++qq) {
            float xv = xp[(size_t)(j4*4+qq) * 512];
            float pq0 = qq==0?p0.x:qq==1?p0.y:qq==2?p0.z:p0.w;
            float pq1 = qq==0?p1.x:qq==1?p1.y:qq==2?p1.z:p1.w;
            float pq2 = qq==0?p2.x:qq==1?p2.y:qq==2?p2.z:p2.w;
            float pq3 = qq==0?p3.x:qq==1?p3.y:qq==2?p3.z:p3.w;
            att0 = fmaf(pq0, xv, att0);
            att1 = fmaf(pq1, xv, att1);
            att2 = fmaf(pq2, xv, att2);
            att3 = fmaf(pq3, xv, att3);
        }
    }
    att0 *= SL[w*4+0][512];
    att1 *= SL[w*4+1][512];
    att2 *= SL[w*4+2][512];
    att3 *= SL[w*4+3][512];

    {
        int ibase = rg * 16 + w * 4;
        ATT[((size_t)(b << 9) + ibase + 0) * 512 + (h << 6) + lane] = att0;
        ATT[((size_t)(b << 9) + ibase + 1) * 512 + (h << 6) + lane] = att1;
        ATT[((size_t)(b << 9) + ibase + 2) * 512 + (h << 6) + lane] = att2;
        ATT[((size_t)(b << 9) + ibase + 3) * 512 + (h << 6) + lane] = att3;
    }
}

// ---------------- LayerNorm + scatter ----------------
__global__ __launch_bounds__(256) void ln_kernel(const float* __restrict__ Cb,
                                                 const float* __restrict__ g,
                                                 const float* __restrict__ beta,
                                                 float* __restrict__ out)
{
    const int w = threadIdx.x >> 6, lane = threadIdx.x & 63;
    const int row = blockIdx.x * 4 + w;
    const int b = row >> 9, l = row & 511;
    const float* x = Cb + (size_t)row * 512;

    float v[8], s = 0.f;
    #pragma unroll
    for (int k = 0; k < 8; ++k) { v[k] = x[k * 64 + lane]; s += v[k]; }
    s = wsum(s);
    float mu = s * (1.f / 512.f);
    float q = 0.f;
    #pragma unroll
    for (int k = 0; k < 8; ++k) { float d = v[k] - mu; q = fmaf(d, d, q); }
    q = wsum(q);
    float rs = rsqrtf(q * (1.f / 512.f) + 1e-12f);

    float* dst = (l < 511) ? (out + (size_t)(b * 511 + l) * 512)
                           : (out + (size_t)16 * 511 * 512 + (size_t)b * 512);
    #pragma unroll
    for (int k = 0; k < 8; ++k) {
        int d = k * 64 + lane;
        dst[d] = (v[k] - mu) * rs * g[d] + beta[d];
    }
}

// ---------------- launch ----------------
extern "C" void kernel_launch(void* const* d_in, const int* in_sizes, int n_in,
                              void* d_out, int out_size, void* d_ws, size_t ws_size,
                              hipStream_t stream)
{
    const float* X    = (const float*)d_in[0];
    const float* mask = (const float*)d_in[1];
    const float* Wq   = (const float*)d_in[2];
    const float* bq   = (const float*)d_in[3];
    const float* W1   = (const float*)d_in[4];
    const float* b1   = (const float*)d_in[5];
    const float* W2   = (const float*)d_in[6];
    const float* b2   = (const float*)d_in[7];
    const float* lng  = (const float*)d_in[8];
    const float* lnb  = (const float*)d_in[9];
    const float* Wa   = (const float*)d_in[10];
    const float* ba   = (const float*)d_in[11];
    float* out = (float*)d_out;
    float* ws  = (float*)d_ws;

    const size_t NE = (size_t)BB * LL * DD;      // 4194304
    const size_t WN = (size_t)DD * DD;           // 262144
    if (ws_size < (3 * NE + 256) * sizeof(float) + 3 * WN * sizeof(ushort_t)) return;

    float* Qb   = ws;
    float* Kt   = ws + NE;
    float* ATT  = ws + 2 * NE;
    float* am1v = ws + 3 * NE;
    float* invv = am1v + 128;
    ushort_t* Wqb = (ushort_t*)(am1v + 256);
    ushort_t* W1b = Wqb + WN;
    ushort_t* W2b = W1b + WN;
    ushort_t* Xb   = (ushort_t*)ATT;
    ushort_t* ATTb = (ushort_t*)Qb;
    ushort_t* Hhb  = (ushort_t*)Qb + NE;
    float* Cb = Kt;

    const int M = BB * LL;       // 8192

    conv_f2b<<<(int)(NE / 1024), 256, 0, stream>>>(X, Xb);
    conv_f2b<<<(int)(WN / 1024), 256, 0, stream>>>(Wq, Wqb);
    gemm_mfma<1, false, false><<<dim3(DD / 64, M / 64), 256, 0, stream>>>(
        Xb, Wqb, bq, nullptr, Qb, M, DD, DD);
    transpose_kt<<<(int)(NE / 256), 256, 0, stream>>>(X, Kt);
    alpha_kernel<<<1, 128, 0, stream>>>(Qb, Wa, ba, am1v, invv);
    attn_kernel<<<BB * HH * LL / 16, 256, 0, stream>>>(Qb, X, Kt, mask, am1v, invv, ATT);
    conv_f2b<<<(int)(NE / 1024), 256, 0, stream>>>(ATT, ATTb);
    conv_f2b<<<(int)(WN / 1024), 256, 0, stream>>>(W1, W1b);
    gemm_mfma<1, false, true><<<dim3(DD / 64, M / 64), 256, 0, stream>>>(
        ATTb, W1b, b1, nullptr, Hhb, M, DD, DD);
    conv_f2b<<<(int)(WN / 1024), 256, 0, stream>>>(W2, W2b);
    gemm_mfma<0, true, false><<<dim3(DD / 64, M / 64), 256, 0, stream>>>(
        Hhb, W2b, b2, ATT, Cb, M, DD, DD);
    ln_kernel<<<M / 4, 256, 0, stream>>>(Cb, lng, lnb, out);
}